// Round 14
// baseline (393.292 us; speedup 1.0000x reference)
//
#include <hip/hip_runtime.h>
#include <hip/hip_bf16.h>
#include <hip/hip_fp16.h>
#include <string.h>

using bf16 = __hip_bfloat16;
typedef __attribute__((ext_vector_type(8))) short short8;       // 8 x bf16 MFMA A/B frag
typedef __attribute__((ext_vector_type(8))) _Float16 half8;     // 8 x fp16 MFMA A/B frag
typedef __attribute__((ext_vector_type(4))) float f32x4;        // 16x16 MFMA C/D frag
typedef __attribute__((ext_vector_type(16))) float f32x16;      // 32x32 MFMA C/D frag

#define GAS __attribute__((address_space(1)))
#define LAS __attribute__((address_space(3)))

__device__ __forceinline__ void gld_lds16(const void* g, void* l) {
  __builtin_amdgcn_global_load_lds((const GAS void*)g, (LAS void*)l, 16, 0, 0);
}

__device__ __forceinline__ unsigned short f2bfu(float f) {
  bf16 h = __float2bfloat16(f);
  return *reinterpret_cast<unsigned short*>(&h);
}

__device__ __forceinline__ unsigned pack_bf16x2(float lo, float hi) {
  __hip_bfloat162 v = __float22bfloat162_rn(make_float2(lo, hi));
  unsigned u;
  __builtin_memcpy(&u, &v, 4);
  return u;
}

__device__ __forceinline__ unsigned pack_f16x2(float lo, float hi) {
  __half2 v = __float22half2_rn(make_float2(lo, hi));
  unsigned u;
  __builtin_memcpy(&u, &v, 4);
  return u;
}

// ---------------- all weights f32 -> bf16 in one launch ----------------
__global__ __launch_bounds__(256) void cvt_all(const float* __restrict__ w0, bf16* __restrict__ o0,
                                               const float* __restrict__ w1, bf16* __restrict__ o1,
                                               const float* __restrict__ w2, bf16* __restrict__ o2,
                                               const float* __restrict__ w3, bf16* __restrict__ o3) {
  int i = blockIdx.x * 256 + threadIdx.x;   // f4 index, total 786432
  const float* src; bf16* dst; int off;
  if (i < 196608)      { src = w0; dst = o0; off = i; }
  else if (i < 262144) { src = w1; dst = o1; off = i - 196608; }
  else if (i < 524288) { src = w2; dst = o2; off = i - 262144; }
  else                 { src = w3; dst = o3; off = i - 524288; }
  float4 v = reinterpret_cast<const float4*>(src)[off];
  ushort4 o;
  o.x = f2bfu(v.x); o.y = f2bfu(v.y); o.z = f2bfu(v.z); o.w = f2bfu(v.w);
  reinterpret_cast<ushort4*>(dst)[off] = o;
}

// ---------------- LayerNorm (fp32 in, bf16 out), one wave per 512-row ----------------
__global__ __launch_bounds__(256) void ln_kernel(const float* __restrict__ x,
                                                 const float* __restrict__ g,
                                                 const float* __restrict__ b,
                                                 bf16* __restrict__ out) {
  const int row = blockIdx.x * 4 + (threadIdx.x >> 6);
  const int lane = threadIdx.x & 63;
  const float4* xr = reinterpret_cast<const float4*>(x + (size_t)row * 512);
  float4 v0 = xr[lane], v1 = xr[64 + lane];
  float s  = v0.x + v0.y + v0.z + v0.w + v1.x + v1.y + v1.z + v1.w;
  float s2 = v0.x*v0.x + v0.y*v0.y + v0.z*v0.z + v0.w*v0.w
           + v1.x*v1.x + v1.y*v1.y + v1.z*v1.z + v1.w*v1.w;
  #pragma unroll
  for (int d = 1; d < 64; d <<= 1) { s += __shfl_xor(s, d); s2 += __shfl_xor(s2, d); }
  const float mu = s * (1.0f / 512.0f);
  const float var = s2 * (1.0f / 512.0f) - mu * mu;
  const float rstd = rsqrtf(var + 1e-5f);
  const float4* g4 = reinterpret_cast<const float4*>(g);
  const float4* b4 = reinterpret_cast<const float4*>(b);
  float4 ga = g4[lane], gb = g4[64 + lane], ba = b4[lane], bb = b4[64 + lane];
  ushort4 o0, o1;
  o0.x = f2bfu((v0.x - mu) * rstd * ga.x + ba.x);
  o0.y = f2bfu((v0.y - mu) * rstd * ga.y + ba.y);
  o0.z = f2bfu((v0.z - mu) * rstd * ga.z + ba.z);
  o0.w = f2bfu((v0.w - mu) * rstd * ga.w + ba.w);
  o1.x = f2bfu((v1.x - mu) * rstd * gb.x + bb.x);
  o1.y = f2bfu((v1.y - mu) * rstd * gb.y + bb.y);
  o1.z = f2bfu((v1.z - mu) * rstd * gb.z + bb.z);
  o1.w = f2bfu((v1.w - mu) * rstd * gb.w + bb.w);
  ushort4* orow = reinterpret_cast<ushort4*>(out + (size_t)row * 512);
  orow[lane] = o0;
  orow[64 + lane] = o1;
}

// ---------------- GEMM 128x128: C[M,N] = A[M,K] * B[N,K]^T (+bias, epilogue) ----------------
// EPI 0: bf16 out. 1: GELU->bf16. 2: +resid(f32)->f32. 3: fp16 out.
template <int EPI>
__global__ __launch_bounds__(256) void gemm_bt(const bf16* __restrict__ A,
                                               const bf16* __restrict__ B,
                                               const float* __restrict__ bias,
                                               const float* __restrict__ resid,
                                               void* __restrict__ Cv,
                                               int M, int N, int K) {
  __shared__ bf16 As[128 * 32];
  __shared__ bf16 Bs[128 * 32];
  const int tid = threadIdx.x;
  const int lane = tid & 63, wid = tid >> 6;
  const int lr = lane & 15, lg = lane >> 4;
  const int row0 = blockIdx.x * 128, col0 = blockIdx.y * 128;
  const int wr = (wid >> 1) * 64, wc = (wid & 1) * 64;
  f32x4 acc[4][4] = {};
  const int r1 = tid >> 2,          c1 = (tid & 3) * 8;
  const int r2 = (256 + tid) >> 2,  c2 = ((256 + tid) & 3) * 8;
  for (int kt = 0; kt < K; kt += 32) {
    __syncthreads();
    gld_lds16(A + (size_t)(row0 + r1) * K + kt + c1, As + tid * 8);
    gld_lds16(A + (size_t)(row0 + r2) * K + kt + c2, As + (256 + tid) * 8);
    gld_lds16(B + (size_t)(col0 + r1) * K + kt + c1, Bs + tid * 8);
    gld_lds16(B + (size_t)(col0 + r2) * K + kt + c2, Bs + (256 + tid) * 8);
    __syncthreads();
    short8 af[4], bfr[4];
    #pragma unroll
    for (int mi = 0; mi < 4; ++mi)
      af[mi] = *reinterpret_cast<const short8*>(&As[(wr + mi * 16 + lr) * 32 + lg * 8]);
    #pragma unroll
    for (int nj = 0; nj < 4; ++nj)
      bfr[nj] = *reinterpret_cast<const short8*>(&Bs[(wc + nj * 16 + lr) * 32 + lg * 8]);
    #pragma unroll
    for (int mi = 0; mi < 4; ++mi)
      #pragma unroll
      for (int nj = 0; nj < 4; ++nj)
        acc[mi][nj] = __builtin_amdgcn_mfma_f32_16x16x32_bf16(af[mi], bfr[nj], acc[mi][nj], 0, 0, 0);
  }
  #pragma unroll
  for (int mi = 0; mi < 4; ++mi) {
    #pragma unroll
    for (int nj = 0; nj < 4; ++nj) {
      const int col = col0 + wc + nj * 16 + lr;
      const float bv = bias ? bias[col] : 0.0f;
      #pragma unroll
      for (int rg = 0; rg < 4; ++rg) {
        const int row = row0 + wr + mi * 16 + lg * 4 + rg;
        float v = acc[mi][nj][rg] + bv;
        if constexpr (EPI == 1) v = 0.5f * v * (1.0f + erff(v * 0.70710678118654752f));
        if constexpr (EPI == 2) {
          reinterpret_cast<float*>(Cv)[(size_t)row * N + col] = v + resid[(size_t)row * N + col];
        } else if constexpr (EPI == 3) {
          reinterpret_cast<__half*>(Cv)[(size_t)row * N + col] = __float2half(v);
        } else {
          reinterpret_cast<bf16*>(Cv)[(size_t)row * N + col] = __float2bfloat16(v);
        }
      }
    }
  }
}

// ---------------- GEMM 64x64 (BK=64, swizzled LDS): for N=512 GEMMs, 1024-block grids ----------------
template <int EPI>
__global__ __launch_bounds__(256) void gemm_bt64(const bf16* __restrict__ A,
                                                 const bf16* __restrict__ B,
                                                 const float* __restrict__ bias,
                                                 const float* __restrict__ resid,
                                                 void* __restrict__ Cv,
                                                 int M, int N, int K) {
  __shared__ bf16 As[64 * 64];   // [64 rows][128B], XOR-swizzled
  __shared__ bf16 Bs[64 * 64];
  const int tid = threadIdx.x;
  const int lane = tid & 63, wid = tid >> 6;
  const int lr = lane & 15, lg = lane >> 4;
  const int row0 = blockIdx.x * 64, col0 = blockIdx.y * 64;
  const int wr = (wid >> 1) * 32, wc = (wid & 1) * 32;
  f32x4 acc[2][2] = {};
  const int xsw = (lr & 7) << 4;
  const int fb0 = lr * 128 + ((lg * 16) ^ xsw);
  const int fb1 = lr * 128 + ((64 + lg * 16) ^ xsw);
  const int ph0 = tid * 16, ph1 = (256 + tid) * 16;
  const int r0 = ph0 >> 7, r1 = ph1 >> 7;
  const int lb0 = ph0 ^ ((r0 & 7) << 4), lb1 = ph1 ^ ((r1 & 7) << 4);
  const char* Ab0 = (const char*)A + (size_t)(row0 + r0) * K * 2 + (lb0 & 127);
  const char* Ab1 = (const char*)A + (size_t)(row0 + r1) * K * 2 + (lb1 & 127);
  const char* Bb0 = (const char*)B + (size_t)(col0 + r0) * K * 2 + (lb0 & 127);
  const char* Bb1 = (const char*)B + (size_t)(col0 + r1) * K * 2 + (lb1 & 127);
  for (int kt = 0; kt < K; kt += 64) {
    __syncthreads();
    gld_lds16(Ab0 + kt * 2, (char*)As + ph0);
    gld_lds16(Ab1 + kt * 2, (char*)As + ph1);
    gld_lds16(Bb0 + kt * 2, (char*)Bs + ph0);
    gld_lds16(Bb1 + kt * 2, (char*)Bs + ph1);
    __syncthreads();
    short8 af0[2], af1[2], bf0[2], bf1[2];
    #pragma unroll
    for (int mi = 0; mi < 2; ++mi) {
      af0[mi] = *reinterpret_cast<const short8*>((const char*)As + (wr + mi * 16) * 128 + fb0);
      af1[mi] = *reinterpret_cast<const short8*>((const char*)As + (wr + mi * 16) * 128 + fb1);
    }
    #pragma unroll
    for (int nj = 0; nj < 2; ++nj) {
      bf0[nj] = *reinterpret_cast<const short8*>((const char*)Bs + (wc + nj * 16) * 128 + fb0);
      bf1[nj] = *reinterpret_cast<const short8*>((const char*)Bs + (wc + nj * 16) * 128 + fb1);
    }
    #pragma unroll
    for (int mi = 0; mi < 2; ++mi)
      #pragma unroll
      for (int nj = 0; nj < 2; ++nj) {
        acc[mi][nj] = __builtin_amdgcn_mfma_f32_16x16x32_bf16(af0[mi], bf0[nj], acc[mi][nj], 0, 0, 0);
        acc[mi][nj] = __builtin_amdgcn_mfma_f32_16x16x32_bf16(af1[mi], bf1[nj], acc[mi][nj], 0, 0, 0);
      }
  }
  #pragma unroll
  for (int mi = 0; mi < 2; ++mi) {
    #pragma unroll
    for (int nj = 0; nj < 2; ++nj) {
      const int col = col0 + wc + nj * 16 + lr;
      const float bv = bias ? bias[col] : 0.0f;
      #pragma unroll
      for (int rg = 0; rg < 4; ++rg) {
        const int row = row0 + wr + mi * 16 + lg * 4 + rg;
        float v = acc[mi][nj][rg] + bv;
        if constexpr (EPI == 1) v = 0.5f * v * (1.0f + erff(v * 0.70710678118654752f));
        if constexpr (EPI == 2) {
          reinterpret_cast<float*>(Cv)[(size_t)row * N + col] = v + resid[(size_t)row * N + col];
        } else {
          reinterpret_cast<bf16*>(Cv)[(size_t)row * N + col] = __float2bfloat16(v);
        }
      }
    }
  }
}

// ---------------- reshape QKV (fp16 in): q [BH,N,64] (scaled); K,V -> 32x32 A-frag-major fp16 ----------------
// KF[bh][t32][dc(4)][lane l][j]: = K[kv = t32*32 + (l&31)][d = dc*16 + (l>>5)*8 + j]
// VF[bh][t32][db(2)][c(2)][lane l][j]: = V[n = t32*32 + c*16 + 4*(l>>5) + (j&3) + 8*(j>>2)][d = db*32 + (l&31)]
__global__ __launch_bounds__(256) void reshape_qkv(const __half* __restrict__ C,
                                                   __half* __restrict__ q,
                                                   __half* __restrict__ KF,
                                                   __half* __restrict__ VF) {
  const int nt = blockIdx.x;   // 64-row tile
  const int bh = blockIdx.y;
  const int b = bh >> 3, h = bh & 7;
  __shared__ alignas(16) __half vs[64][72];  // [d][n] transposed tile
  const int tid = threadIdx.x;
  const float qs = 0.125f * 1.44269504088896340736f;
  #pragma unroll
  for (int i = 0; i < 16; ++i) {
    const int idx = i * 256 + tid;
    const int rr = idx >> 6, c = idx & 63;
    const size_t crow = ((size_t)b * 4096 + nt * 64 + rr) * 1536;
    const size_t onb = ((size_t)bh * 4096 + nt * 64 + rr) * 64 + c;
    q[onb] = __float2half(__half2float(C[crow + h * 64 + c]) * qs);
    vs[c][rr] = C[crow + 1024 + h * 64 + c];   // transposed: vs[d][n]
  }
  // K frag-major (contiguous 16B source chunks, no LDS needed)
  #pragma unroll
  for (int i = 0; i < 2; ++i) {
    const int s = i * 256 + tid;               // 0..511
    const int half_ = s >> 8, dc = (s >> 6) & 3, l = s & 63;
    const int l31 = l & 31, hi2 = l >> 5;
    const __half* src = C + ((size_t)b * 4096 + nt * 64 + half_ * 32 + l31) * 1536
                          + 512 + h * 64 + dc * 16 + hi2 * 8;
    __half* dst = KF + ((size_t)bh * 128 + nt * 2 + half_) * 2048 + dc * 512 + (size_t)l * 8;
    *reinterpret_cast<short8*>(dst) = *reinterpret_cast<const short8*>(src);
  }
  __syncthreads();
  #pragma unroll
  for (int i = 0; i < 2; ++i) {
    const int s = i * 256 + tid;               // 0..511
    const int half_ = (s >> 8) & 1, db = (s >> 7) & 1, c = (s >> 6) & 1, l = s & 63;
    const int d = db * 32 + (l & 31);
    const int n0 = half_ * 32 + c * 16 + ((l >> 5) << 2);
    const short4 lo = *reinterpret_cast<const short4*>(&vs[d][n0]);
    const short4 hi = *reinterpret_cast<const short4*>(&vs[d][n0 + 8]);
    short8 v;
    v[0] = lo.x; v[1] = lo.y; v[2] = lo.z; v[3] = lo.w;
    v[4] = hi.x; v[5] = hi.y; v[6] = hi.z; v[7] = hi.w;
    __half* dst = VF + ((size_t)bh * 128 + nt * 2 + half_) * 2048 + (db * 2 + c) * 512 + (size_t)l * 8;
    *reinterpret_cast<short8*>(dst) = v;
  }
}

// ---------------- flash attention: fp16 32x32 MFMA, 64 q/wave, 4-way KV split, barrier-free loop ----------------
// Block = 4 waves over the SAME 64 q-rows; wave w owns KV quarter w (32 tiles). 3-round merge at end.
__global__ __launch_bounds__(256, 4) void attn_kernel(const __half* __restrict__ Q,
                                                      const __half* __restrict__ KF,
                                                      const __half* __restrict__ VF,
                                                      bf16* __restrict__ Out) {
  const int qt = blockIdx.x;   // 0..63 (64 q rows per block)
  const int bh = blockIdx.y;   // 0..15
  const int b = bh >> 3, h = bh & 7;
  __shared__ alignas(16) char smem[17408];   // merge only: 2 areas (one per q-set) x 8704B
  const int tid = threadIdx.x, w = tid >> 6, lane = tid & 63;  // w = kv quarter 0..3
  const int l31 = lane & 31, hi = lane >> 5;

  // ---- Q frags for both q-sets (B operand: col=q=l31, k-slots hi*8+j) ----
  const __half* qbase = Q + ((size_t)bh * 4096 + qt * 64 + l31) * 64 + hi * 8;
  half8 qf0[4], qf1[4];
  #pragma unroll
  for (int dc = 0; dc < 4; ++dc) {
    qf0[dc] = *reinterpret_cast<const half8*>(qbase + dc * 16);
    qf1[dc] = *reinterpret_cast<const half8*>(qbase + 2048 + dc * 16);  // +32 rows
  }

  const char* kfp = (const char*)KF + (size_t)bh * 524288 + (size_t)w * 131072 + lane * 16;
  const char* vfp = (const char*)VF + (size_t)bh * 524288 + (size_t)w * 131072 + lane * 16;

  f32x16 O00 = {}, O01 = {};   // q-set 0: d 0..31 / d 32..63
  f32x16 O10 = {}, O11 = {};   // q-set 1
  float m0 = -1e30f, l0 = 0.0f, m1 = -1e30f, l1 = 0.0f;

  for (int t = 0; t < 32; ++t) {
    const half8 va00 = *reinterpret_cast<const half8*>(vfp);
    const half8 va01 = *reinterpret_cast<const half8*>(vfp + 1024);
    const half8 va10 = *reinterpret_cast<const half8*>(vfp + 2048);
    const half8 va11 = *reinterpret_cast<const half8*>(vfp + 3072);
    vfp += 4096;
    const half8 kf0 = *reinterpret_cast<const half8*>(kfp);
    const half8 kf1 = *reinterpret_cast<const half8*>(kfp + 1024);
    const half8 kf2 = *reinterpret_cast<const half8*>(kfp + 2048);
    const half8 kf3 = *reinterpret_cast<const half8*>(kfp + 3072);
    kfp += 4096;
    // ---- S^T[kv][q] for both q-sets ----
    f32x16 S0 = {}, S1 = {};
    __builtin_amdgcn_s_setprio(1);
    S0 = __builtin_amdgcn_mfma_f32_32x32x16_f16(kf0, qf0[0], S0, 0, 0, 0);
    S1 = __builtin_amdgcn_mfma_f32_32x32x16_f16(kf0, qf1[0], S1, 0, 0, 0);
    S0 = __builtin_amdgcn_mfma_f32_32x32x16_f16(kf1, qf0[1], S0, 0, 0, 0);
    S1 = __builtin_amdgcn_mfma_f32_32x32x16_f16(kf1, qf1[1], S1, 0, 0, 0);
    S0 = __builtin_amdgcn_mfma_f32_32x32x16_f16(kf2, qf0[2], S0, 0, 0, 0);
    S1 = __builtin_amdgcn_mfma_f32_32x32x16_f16(kf2, qf1[2], S1, 0, 0, 0);
    S0 = __builtin_amdgcn_mfma_f32_32x32x16_f16(kf3, qf0[3], S0, 0, 0, 0);
    S1 = __builtin_amdgcn_mfma_f32_32x32x16_f16(kf3, qf1[3], S1, 0, 0, 0);
    __builtin_amdgcn_s_setprio(0);
    union U8 { unsigned u[4]; half8 h8; } p00, p01, p10, p11;
    // ---- softmax + pack, q-set 0 ----
    {
      float a0 = fmaxf(fmaxf(S0[0], S0[1]), fmaxf(S0[2], S0[3]));
      float a1 = fmaxf(fmaxf(S0[4], S0[5]), fmaxf(S0[6], S0[7]));
      float a2 = fmaxf(fmaxf(S0[8], S0[9]), fmaxf(S0[10], S0[11]));
      float a3 = fmaxf(fmaxf(S0[12], S0[13]), fmaxf(S0[14], S0[15]));
      float rmax = fmaxf(fmaxf(a0, a1), fmaxf(a2, a3));
      rmax = fmaxf(rmax, __shfl_xor(rmax, 32));
      if (!__all(rmax <= m0 + 8.0f)) {
        const float mnew = fmaxf(m0, rmax);
        const float fsc = __builtin_amdgcn_exp2f(m0 - mnew);
        l0 *= fsc;
        #pragma unroll
        for (int i = 0; i < 16; ++i) { O00[i] *= fsc; O01[i] *= fsc; }
        m0 = mnew;
      }
      #pragma unroll
      for (int i = 0; i < 16; ++i) S0[i] = __builtin_amdgcn_exp2f(S0[i] - m0);
      float s0 = (S0[0] + S0[1]) + (S0[2] + S0[3]);
      float s1 = (S0[4] + S0[5]) + (S0[6] + S0[7]);
      float s2 = (S0[8] + S0[9]) + (S0[10] + S0[11]);
      float s3 = (S0[12] + S0[13]) + (S0[14] + S0[15]);
      float rsum = (s0 + s1) + (s2 + s3);
      rsum += __shfl_xor(rsum, 32);
      l0 += rsum;
      p00.u[0] = pack_f16x2(S0[0], S0[1]);   p00.u[1] = pack_f16x2(S0[2], S0[3]);
      p00.u[2] = pack_f16x2(S0[4], S0[5]);   p00.u[3] = pack_f16x2(S0[6], S0[7]);
      p01.u[0] = pack_f16x2(S0[8], S0[9]);   p01.u[1] = pack_f16x2(S0[10], S0[11]);
      p01.u[2] = pack_f16x2(S0[12], S0[13]); p01.u[3] = pack_f16x2(S0[14], S0[15]);
    }
    // ---- softmax + pack, q-set 1 ----
    {
      float a0 = fmaxf(fmaxf(S1[0], S1[1]), fmaxf(S1[2], S1[3]));
      float a1 = fmaxf(fmaxf(S1[4], S1[5]), fmaxf(S1[6], S1[7]));
      float a2 = fmaxf(fmaxf(S1[8], S1[9]), fmaxf(S1[10], S1[11]));
      float a3 = fmaxf(fmaxf(S1[12], S1[13]), fmaxf(S1[14], S1[15]));
      float rmax = fmaxf(fmaxf(a0, a1), fmaxf(a2, a3));
      rmax = fmaxf(rmax, __shfl_xor(rmax, 32));
      if (!__all(rmax <= m1 + 8.0f)) {
        const float mnew = fmaxf(m1, rmax);
        const float fsc = __builtin_amdgcn_exp2f(m1 - mnew);
        l1 *= fsc;
        #pragma unroll
        for (int i = 0; i < 16; ++i) { O10[i] *= fsc; O11[i] *= fsc; }
        m1 = mnew;
      }
      #pragma unroll
      for (int i = 0; i < 16; ++i) S1[i] = __builtin_amdgcn_exp2f(S1[i] - m1);
      float s0 = (S1[0] + S1[1]) + (S1[2] + S1[3]);
      float s1 = (S1[4] + S1[5]) + (S1[6] + S1[7]);
      float s2 = (S1[8] + S1[9]) + (S1[10] + S1[11]);
      float s3 = (S1[12] + S1[13]) + (S1[14] + S1[15]);
      float rsum = (s0 + s1) + (s2 + s3);
      rsum += __shfl_xor(rsum, 32);
      l1 += rsum;
      p10.u[0] = pack_f16x2(S1[0], S1[1]);   p10.u[1] = pack_f16x2(S1[2], S1[3]);
      p10.u[2] = pack_f16x2(S1[4], S1[5]);   p10.u[3] = pack_f16x2(S1[6], S1[7]);
      p11.u[0] = pack_f16x2(S1[8], S1[9]);   p11.u[1] = pack_f16x2(S1[10], S1[11]);
      p11.u[2] = pack_f16x2(S1[12], S1[13]); p11.u[3] = pack_f16x2(S1[14], S1[15]);
    }
    // ---- O^T[d][q] += V^T . P^T (both q-sets share the V frags) ----
    __builtin_amdgcn_s_setprio(1);
    O00 = __builtin_amdgcn_mfma_f32_32x32x16_f16(va00, p00.h8, O00, 0, 0, 0);
    O10 = __builtin_amdgcn_mfma_f32_32x32x16_f16(va00, p10.h8, O10, 0, 0, 0);
    O00 = __builtin_amdgcn_mfma_f32_32x32x16_f16(va01, p01.h8, O00, 0, 0, 0);
    O10 = __builtin_amdgcn_mfma_f32_32x32x16_f16(va01, p11.h8, O10, 0, 0, 0);
    O01 = __builtin_amdgcn_mfma_f32_32x32x16_f16(va10, p00.h8, O01, 0, 0, 0);
    O11 = __builtin_amdgcn_mfma_f32_32x32x16_f16(va10, p10.h8, O11, 0, 0, 0);
    O01 = __builtin_amdgcn_mfma_f32_32x32x16_f16(va11, p01.h8, O01, 0, 0, 0);
    O11 = __builtin_amdgcn_mfma_f32_32x32x16_f16(va11, p11.h8, O11, 0, 0, 0);
    __builtin_amdgcn_s_setprio(0);
  }

  // ---- 3-round merge: waves 1..3 publish, wave 0 folds (exact f32) ----
  float* area0 = reinterpret_cast<float*>(smem);          // q-set 0: 2048 O + 64 m + 64 l
  float* area1 = reinterpret_cast<float*>(smem) + 2176;   // q-set 1
  for (int r = 1; r < 4; ++r) {
    __syncthreads();
    if (w == r) {
      #pragma unroll
      for (int i = 0; i < 16; ++i) {
        area0[i * 64 + lane] = O00[i];
        area0[(16 + i) * 64 + lane] = O01[i];
        area1[i * 64 + lane] = O10[i];
        area1[(16 + i) * 64 + lane] = O11[i];
      }
      area0[2048 + lane] = m0;  area0[2112 + lane] = l0;
      area1[2048 + lane] = m1;  area1[2112 + lane] = l1;
    }
    __syncthreads();
    if (w == 0) {
      {
        const float mB = area0[2048 + lane], lB = area0[2112 + lane];
        const float mx = fmaxf(m0, mB);
        const float fa = __builtin_amdgcn_exp2f(m0 - mx);
        const float fb = __builtin_amdgcn_exp2f(mB - mx);
        #pragma unroll
        for (int i = 0; i < 16; ++i) {
          O00[i] = O00[i] * fa + area0[i * 64 + lane] * fb;
          O01[i] = O01[i] * fa + area0[(16 + i) * 64 + lane] * fb;
        }
        l0 = l0 * fa + lB * fb;
        m0 = mx;
      }
      {
        const float mB = area1[2048 + lane], lB = area1[2112 + lane];
        const float mx = fmaxf(m1, mB);
        const float fa = __builtin_amdgcn_exp2f(m1 - mx);
        const float fb = __builtin_amdgcn_exp2f(mB - mx);
        #pragma unroll
        for (int i = 0; i < 16; ++i) {
          O10[i] = O10[i] * fa + area1[i * 64 + lane] * fb;
          O11[i] = O11[i] * fa + area1[(16 + i) * 64 + lane] * fb;
        }
        l1 = l1 * fa + lB * fb;
        m1 = mx;
      }
    }
  }
  // ---- normalize + store (wave 0 only) ----
  if (w == 0) {
    #pragma unroll
    for (int qs = 0; qs < 2; ++qs) {
      const f32x16& Pd0 = qs ? O10 : O00;
      const f32x16& Pd1 = qs ? O11 : O01;
      const float inv = 1.0f / (qs ? l1 : l0);
      const int qrow2 = qt * 64 + qs * 32 + l31;
      bf16* ob = Out + ((size_t)b * 4096 + qrow2) * 512 + h * 64 + hi * 4;
      #pragma unroll
      for (int db = 0; db < 2; ++db) {
        #pragma unroll
        for (int rq = 0; rq < 4; ++rq) {
          const int r = rq * 4;
          uint2 st;
          st.x = pack_bf16x2((db ? Pd1[r + 0] : Pd0[r + 0]) * inv,
                             (db ? Pd1[r + 1] : Pd0[r + 1]) * inv);
          st.y = pack_bf16x2((db ? Pd1[r + 2] : Pd0[r + 2]) * inv,
                             (db ? Pd1[r + 3] : Pd0[r + 3]) * inv);
          *reinterpret_cast<uint2*>(ob + db * 32 + rq * 8) = st;
        }
      }
    }
  }
}

// ---------------- host ----------------
extern "C" void kernel_launch(void* const* d_in, const int* in_sizes, int n_in,
                              void* d_out, int out_size, void* d_ws, size_t ws_size,
                              hipStream_t stream) {
  const float* x      = (const float*)d_in[0];
  const float* ln1_g  = (const float*)d_in[1];
  const float* ln1_b  = (const float*)d_in[2];
  const float* ln2_g  = (const float*)d_in[3];
  const float* ln2_b  = (const float*)d_in[4];
  const float* qkv_w  = (const float*)d_in[5];
  const float* qkv_b  = (const float*)d_in[6];
  const float* proj_w = (const float*)d_in[7];
  const float* proj_b = (const float*)d_in[8];
  const float* fc1_w  = (const float*)d_in[9];
  const float* fc1_b  = (const float*)d_in[10];
  const float* fc2_w  = (const float*)d_in[11];
  const float* fc2_b  = (const float*)d_in[12];

  char* ws = (char*)d_ws;
  constexpr size_t o_qkvw = 0;
  constexpr size_t o_projw = 1572864;
  constexpr size_t o_fc1w  = 2097152;
  constexpr size_t o_fc2w  = 4194304;
  constexpr size_t o_h     = 6291456;
  constexpr size_t o_qkvC  = 14680064;
  constexpr size_t o_q     = 39845888;
  constexpr size_t o_k     = 48234496;
  constexpr size_t o_vt    = 56623104;
  constexpr size_t o_attn  = 65011712;
  constexpr size_t o_x2    = 73400320;
  constexpr size_t o_fc1o  = o_qkvC;
  constexpr size_t needed  = 90177536;
  if (ws_size < needed) return;

  bf16* qkvw_bf = (bf16*)(ws + o_qkvw);
  bf16* projw_bf = (bf16*)(ws + o_projw);
  bf16* fc1w_bf = (bf16*)(ws + o_fc1w);
  bf16* fc2w_bf = (bf16*)(ws + o_fc2w);
  bf16* h     = (bf16*)(ws + o_h);
  __half* qkvC = (__half*)(ws + o_qkvC);
  __half* q    = (__half*)(ws + o_q);
  __half* kf   = (__half*)(ws + o_k);
  __half* vf   = (__half*)(ws + o_vt);
  bf16* attn  = (bf16*)(ws + o_attn);
  float* x2   = (float*)(ws + o_x2);
  bf16* fc1o  = (bf16*)(ws + o_fc1o);
  float* out  = (float*)d_out;

  cvt_all<<<3072, 256, 0, stream>>>(qkv_w, qkvw_bf, proj_w, projw_bf, fc1_w, fc1w_bf, fc2_w, fc2w_bf);

  ln_kernel<<<2048, 256, 0, stream>>>(x, ln1_g, ln1_b, h);
  gemm_bt<3><<<dim3(64, 12), 256, 0, stream>>>(h, qkvw_bf, qkv_b, nullptr, qkvC, 8192, 1536, 512);
  reshape_qkv<<<dim3(64, 16), 256, 0, stream>>>(qkvC, q, kf, vf);
  attn_kernel<<<dim3(64, 16), 256, 0, stream>>>(q, kf, vf, attn);
  gemm_bt64<2><<<dim3(128, 8), 256, 0, stream>>>(attn, projw_bf, proj_b, x, x2, 8192, 512, 512);
  ln_kernel<<<2048, 256, 0, stream>>>(x2, ln2_g, ln2_b, h);
  gemm_bt<1><<<dim3(64, 16), 256, 0, stream>>>(h, fc1w_bf, fc1_b, nullptr, fc1o, 8192, 2048, 512);
  gemm_bt64<2><<<dim3(128, 8), 256, 0, stream>>>(fc1o, fc2w_bf, fc2_b, x2, out, 8192, 512, 2048);
}

// Round 15
// 242.608 us; speedup vs baseline: 1.6211x; 1.6211x over previous
//
#include <hip/hip_runtime.h>
#include <hip/hip_bf16.h>
#include <hip/hip_fp16.h>
#include <string.h>

using bf16 = __hip_bfloat16;
typedef __attribute__((ext_vector_type(8))) short short8;       // 8 x bf16 MFMA A/B frag
typedef __attribute__((ext_vector_type(8))) _Float16 half8;     // 8 x fp16 MFMA A/B frag
typedef __attribute__((ext_vector_type(4))) float f32x4;        // 16x16 MFMA C/D frag
typedef __attribute__((ext_vector_type(16))) float f32x16;      // 32x32 MFMA C/D frag

#define GAS __attribute__((address_space(1)))
#define LAS __attribute__((address_space(3)))

__device__ __forceinline__ void gld_lds16(const void* g, void* l) {
  __builtin_amdgcn_global_load_lds((const GAS void*)g, (LAS void*)l, 16, 0, 0);
}

__device__ __forceinline__ unsigned short f2bfu(float f) {
  bf16 h = __float2bfloat16(f);
  return *reinterpret_cast<unsigned short*>(&h);
}

__device__ __forceinline__ unsigned pack_bf16x2(float lo, float hi) {
  __hip_bfloat162 v = __float22bfloat162_rn(make_float2(lo, hi));
  unsigned u;
  __builtin_memcpy(&u, &v, 4);
  return u;
}

__device__ __forceinline__ unsigned pack_f16x2(float lo, float hi) {
  __half2 v = __float22half2_rn(make_float2(lo, hi));
  unsigned u;
  __builtin_memcpy(&u, &v, 4);
  return u;
}

// ---------------- all weights f32 -> bf16 in one launch ----------------
__global__ __launch_bounds__(256) void cvt_all(const float* __restrict__ w0, bf16* __restrict__ o0,
                                               const float* __restrict__ w1, bf16* __restrict__ o1,
                                               const float* __restrict__ w2, bf16* __restrict__ o2,
                                               const float* __restrict__ w3, bf16* __restrict__ o3) {
  int i = blockIdx.x * 256 + threadIdx.x;   // f4 index, total 786432
  const float* src; bf16* dst; int off;
  if (i < 196608)      { src = w0; dst = o0; off = i; }
  else if (i < 262144) { src = w1; dst = o1; off = i - 196608; }
  else if (i < 524288) { src = w2; dst = o2; off = i - 262144; }
  else                 { src = w3; dst = o3; off = i - 524288; }
  float4 v = reinterpret_cast<const float4*>(src)[off];
  ushort4 o;
  o.x = f2bfu(v.x); o.y = f2bfu(v.y); o.z = f2bfu(v.z); o.w = f2bfu(v.w);
  reinterpret_cast<ushort4*>(dst)[off] = o;
}

// ---------------- LayerNorm (fp32 in, bf16 out), one wave per 512-row ----------------
__global__ __launch_bounds__(256) void ln_kernel(const float* __restrict__ x,
                                                 const float* __restrict__ g,
                                                 const float* __restrict__ b,
                                                 bf16* __restrict__ out) {
  const int row = blockIdx.x * 4 + (threadIdx.x >> 6);
  const int lane = threadIdx.x & 63;
  const float4* xr = reinterpret_cast<const float4*>(x + (size_t)row * 512);
  float4 v0 = xr[lane], v1 = xr[64 + lane];
  float s  = v0.x + v0.y + v0.z + v0.w + v1.x + v1.y + v1.z + v1.w;
  float s2 = v0.x*v0.x + v0.y*v0.y + v0.z*v0.z + v0.w*v0.w
           + v1.x*v1.x + v1.y*v1.y + v1.z*v1.z + v1.w*v1.w;
  #pragma unroll
  for (int d = 1; d < 64; d <<= 1) { s += __shfl_xor(s, d); s2 += __shfl_xor(s2, d); }
  const float mu = s * (1.0f / 512.0f);
  const float var = s2 * (1.0f / 512.0f) - mu * mu;
  const float rstd = rsqrtf(var + 1e-5f);
  const float4* g4 = reinterpret_cast<const float4*>(g);
  const float4* b4 = reinterpret_cast<const float4*>(b);
  float4 ga = g4[lane], gb = g4[64 + lane], ba = b4[lane], bb = b4[64 + lane];
  ushort4 o0, o1;
  o0.x = f2bfu((v0.x - mu) * rstd * ga.x + ba.x);
  o0.y = f2bfu((v0.y - mu) * rstd * ga.y + ba.y);
  o0.z = f2bfu((v0.z - mu) * rstd * ga.z + ba.z);
  o0.w = f2bfu((v0.w - mu) * rstd * ga.w + ba.w);
  o1.x = f2bfu((v1.x - mu) * rstd * gb.x + bb.x);
  o1.y = f2bfu((v1.y - mu) * rstd * gb.y + bb.y);
  o1.z = f2bfu((v1.z - mu) * rstd * gb.z + bb.z);
  o1.w = f2bfu((v1.w - mu) * rstd * gb.w + bb.w);
  ushort4* orow = reinterpret_cast<ushort4*>(out + (size_t)row * 512);
  orow[lane] = o0;
  orow[64 + lane] = o1;
}

// ---------------- GEMM 128x128: C[M,N] = A[M,K] * B[N,K]^T (+bias, epilogue) ----------------
// EPI 0: bf16 out. 1: GELU->bf16. 2: +resid(f32)->f32. 3: fp16 out.
template <int EPI>
__global__ __launch_bounds__(256) void gemm_bt(const bf16* __restrict__ A,
                                               const bf16* __restrict__ B,
                                               const float* __restrict__ bias,
                                               const float* __restrict__ resid,
                                               void* __restrict__ Cv,
                                               int M, int N, int K) {
  __shared__ bf16 As[128 * 32];
  __shared__ bf16 Bs[128 * 32];
  const int tid = threadIdx.x;
  const int lane = tid & 63, wid = tid >> 6;
  const int lr = lane & 15, lg = lane >> 4;
  const int row0 = blockIdx.x * 128, col0 = blockIdx.y * 128;
  const int wr = (wid >> 1) * 64, wc = (wid & 1) * 64;
  f32x4 acc[4][4] = {};
  const int r1 = tid >> 2,          c1 = (tid & 3) * 8;
  const int r2 = (256 + tid) >> 2,  c2 = ((256 + tid) & 3) * 8;
  for (int kt = 0; kt < K; kt += 32) {
    __syncthreads();
    gld_lds16(A + (size_t)(row0 + r1) * K + kt + c1, As + tid * 8);
    gld_lds16(A + (size_t)(row0 + r2) * K + kt + c2, As + (256 + tid) * 8);
    gld_lds16(B + (size_t)(col0 + r1) * K + kt + c1, Bs + tid * 8);
    gld_lds16(B + (size_t)(col0 + r2) * K + kt + c2, Bs + (256 + tid) * 8);
    __syncthreads();
    short8 af[4], bfr[4];
    #pragma unroll
    for (int mi = 0; mi < 4; ++mi)
      af[mi] = *reinterpret_cast<const short8*>(&As[(wr + mi * 16 + lr) * 32 + lg * 8]);
    #pragma unroll
    for (int nj = 0; nj < 4; ++nj)
      bfr[nj] = *reinterpret_cast<const short8*>(&Bs[(wc + nj * 16 + lr) * 32 + lg * 8]);
    #pragma unroll
    for (int mi = 0; mi < 4; ++mi)
      #pragma unroll
      for (int nj = 0; nj < 4; ++nj)
        acc[mi][nj] = __builtin_amdgcn_mfma_f32_16x16x32_bf16(af[mi], bfr[nj], acc[mi][nj], 0, 0, 0);
  }
  #pragma unroll
  for (int mi = 0; mi < 4; ++mi) {
    #pragma unroll
    for (int nj = 0; nj < 4; ++nj) {
      const int col = col0 + wc + nj * 16 + lr;
      const float bv = bias ? bias[col] : 0.0f;
      #pragma unroll
      for (int rg = 0; rg < 4; ++rg) {
        const int row = row0 + wr + mi * 16 + lg * 4 + rg;
        float v = acc[mi][nj][rg] + bv;
        if constexpr (EPI == 1) v = 0.5f * v * (1.0f + erff(v * 0.70710678118654752f));
        if constexpr (EPI == 2) {
          reinterpret_cast<float*>(Cv)[(size_t)row * N + col] = v + resid[(size_t)row * N + col];
        } else if constexpr (EPI == 3) {
          reinterpret_cast<__half*>(Cv)[(size_t)row * N + col] = __float2half(v);
        } else {
          reinterpret_cast<bf16*>(Cv)[(size_t)row * N + col] = __float2bfloat16(v);
        }
      }
    }
  }
}

// ---------------- GEMM 64x64 (BK=64, swizzled LDS): for N=512 GEMMs, 1024-block grids ----------------
template <int EPI>
__global__ __launch_bounds__(256) void gemm_bt64(const bf16* __restrict__ A,
                                                 const bf16* __restrict__ B,
                                                 const float* __restrict__ bias,
                                                 const float* __restrict__ resid,
                                                 void* __restrict__ Cv,
                                                 int M, int N, int K) {
  __shared__ bf16 As[64 * 64];   // [64 rows][128B], XOR-swizzled
  __shared__ bf16 Bs[64 * 64];
  const int tid = threadIdx.x;
  const int lane = tid & 63, wid = tid >> 6;
  const int lr = lane & 15, lg = lane >> 4;
  const int row0 = blockIdx.x * 64, col0 = blockIdx.y * 64;
  const int wr = (wid >> 1) * 32, wc = (wid & 1) * 32;
  f32x4 acc[2][2] = {};
  const int xsw = (lr & 7) << 4;
  const int fb0 = lr * 128 + ((lg * 16) ^ xsw);
  const int fb1 = lr * 128 + ((64 + lg * 16) ^ xsw);
  const int ph0 = tid * 16, ph1 = (256 + tid) * 16;
  const int r0 = ph0 >> 7, r1 = ph1 >> 7;
  const int lb0 = ph0 ^ ((r0 & 7) << 4), lb1 = ph1 ^ ((r1 & 7) << 4);
  const char* Ab0 = (const char*)A + (size_t)(row0 + r0) * K * 2 + (lb0 & 127);
  const char* Ab1 = (const char*)A + (size_t)(row0 + r1) * K * 2 + (lb1 & 127);
  const char* Bb0 = (const char*)B + (size_t)(col0 + r0) * K * 2 + (lb0 & 127);
  const char* Bb1 = (const char*)B + (size_t)(col0 + r1) * K * 2 + (lb1 & 127);
  for (int kt = 0; kt < K; kt += 64) {
    __syncthreads();
    gld_lds16(Ab0 + kt * 2, (char*)As + ph0);
    gld_lds16(Ab1 + kt * 2, (char*)As + ph1);
    gld_lds16(Bb0 + kt * 2, (char*)Bs + ph0);
    gld_lds16(Bb1 + kt * 2, (char*)Bs + ph1);
    __syncthreads();
    short8 af0[2], af1[2], bf0[2], bf1[2];
    #pragma unroll
    for (int mi = 0; mi < 2; ++mi) {
      af0[mi] = *reinterpret_cast<const short8*>((const char*)As + (wr + mi * 16) * 128 + fb0);
      af1[mi] = *reinterpret_cast<const short8*>((const char*)As + (wr + mi * 16) * 128 + fb1);
    }
    #pragma unroll
    for (int nj = 0; nj < 2; ++nj) {
      bf0[nj] = *reinterpret_cast<const short8*>((const char*)Bs + (wc + nj * 16) * 128 + fb0);
      bf1[nj] = *reinterpret_cast<const short8*>((const char*)Bs + (wc + nj * 16) * 128 + fb1);
    }
    #pragma unroll
    for (int mi = 0; mi < 2; ++mi)
      #pragma unroll
      for (int nj = 0; nj < 2; ++nj) {
        acc[mi][nj] = __builtin_amdgcn_mfma_f32_16x16x32_bf16(af0[mi], bf0[nj], acc[mi][nj], 0, 0, 0);
        acc[mi][nj] = __builtin_amdgcn_mfma_f32_16x16x32_bf16(af1[mi], bf1[nj], acc[mi][nj], 0, 0, 0);
      }
  }
  #pragma unroll
  for (int mi = 0; mi < 2; ++mi) {
    #pragma unroll
    for (int nj = 0; nj < 2; ++nj) {
      const int col = col0 + wc + nj * 16 + lr;
      const float bv = bias ? bias[col] : 0.0f;
      #pragma unroll
      for (int rg = 0; rg < 4; ++rg) {
        const int row = row0 + wr + mi * 16 + lg * 4 + rg;
        float v = acc[mi][nj][rg] + bv;
        if constexpr (EPI == 1) v = 0.5f * v * (1.0f + erff(v * 0.70710678118654752f));
        if constexpr (EPI == 2) {
          reinterpret_cast<float*>(Cv)[(size_t)row * N + col] = v + resid[(size_t)row * N + col];
        } else {
          reinterpret_cast<bf16*>(Cv)[(size_t)row * N + col] = __float2bfloat16(v);
        }
      }
    }
  }
}

// ---------------- reshape QKV (fp16 in): q [BH,N,64] (scaled); K,V -> 32x32 A-frag-major fp16 ----------------
// KF[bh][t32][dc(4)][lane l][j]: = K[kv = t32*32 + (l&31)][d = dc*16 + (l>>5)*8 + j]
// VF[bh][t32][db(2)][c(2)][lane l][j]: = V[n = t32*32 + c*16 + 4*(l>>5) + (j&3) + 8*(j>>2)][d = db*32 + (l&31)]
__global__ __launch_bounds__(256) void reshape_qkv(const __half* __restrict__ C,
                                                   __half* __restrict__ q,
                                                   __half* __restrict__ KF,
                                                   __half* __restrict__ VF) {
  const int nt = blockIdx.x;   // 64-row tile
  const int bh = blockIdx.y;
  const int b = bh >> 3, h = bh & 7;
  __shared__ alignas(16) __half vs[64][72];  // [d][n] transposed tile
  const int tid = threadIdx.x;
  const float qs = 0.125f * 1.44269504088896340736f;
  #pragma unroll
  for (int i = 0; i < 16; ++i) {
    const int idx = i * 256 + tid;
    const int rr = idx >> 6, c = idx & 63;
    const size_t crow = ((size_t)b * 4096 + nt * 64 + rr) * 1536;
    const size_t onb = ((size_t)bh * 4096 + nt * 64 + rr) * 64 + c;
    q[onb] = __float2half(__half2float(C[crow + h * 64 + c]) * qs);
    vs[c][rr] = C[crow + 1024 + h * 64 + c];   // transposed: vs[d][n]
  }
  // K frag-major (contiguous 16B source chunks, no LDS needed)
  #pragma unroll
  for (int i = 0; i < 2; ++i) {
    const int s = i * 256 + tid;               // 0..511
    const int half_ = s >> 8, dc = (s >> 6) & 3, l = s & 63;
    const int l31 = l & 31, hi2 = l >> 5;
    const __half* src = C + ((size_t)b * 4096 + nt * 64 + half_ * 32 + l31) * 1536
                          + 512 + h * 64 + dc * 16 + hi2 * 8;
    __half* dst = KF + ((size_t)bh * 128 + nt * 2 + half_) * 2048 + dc * 512 + (size_t)l * 8;
    *reinterpret_cast<short8*>(dst) = *reinterpret_cast<const short8*>(src);
  }
  __syncthreads();
  #pragma unroll
  for (int i = 0; i < 2; ++i) {
    const int s = i * 256 + tid;               // 0..511
    const int half_ = (s >> 8) & 1, db = (s >> 7) & 1, c = (s >> 6) & 1, l = s & 63;
    const int d = db * 32 + (l & 31);
    const int n0 = half_ * 32 + c * 16 + ((l >> 5) << 2);
    const short4 lo = *reinterpret_cast<const short4*>(&vs[d][n0]);
    const short4 hi = *reinterpret_cast<const short4*>(&vs[d][n0 + 8]);
    short8 v;
    v[0] = lo.x; v[1] = lo.y; v[2] = lo.z; v[3] = lo.w;
    v[4] = hi.x; v[5] = hi.y; v[6] = hi.z; v[7] = hi.w;
    __half* dst = VF + ((size_t)bh * 128 + nt * 2 + half_) * 2048 + (db * 2 + c) * 512 + (size_t)l * 8;
    *reinterpret_cast<short8*>(dst) = v;
  }
}

// ---------------- flash attention: fp16 32x32 MFMA, 64 q/wave, 4-way KV split, barrier-free loop ----------------
// Block = 4 waves over the SAME 64 q-rows; wave w owns KV quarter w (32 tiles). 3-round merge at end.
// R15: launch_bounds (256,2) — (256,4) forced a 128-reg unified cap -> scratch spill (R14: 748MB fetch).
__global__ __launch_bounds__(256, 2) void attn_kernel(const __half* __restrict__ Q,
                                                      const __half* __restrict__ KF,
                                                      const __half* __restrict__ VF,
                                                      bf16* __restrict__ Out) {
  const int qt = blockIdx.x;   // 0..63 (64 q rows per block)
  const int bh = blockIdx.y;   // 0..15
  const int b = bh >> 3, h = bh & 7;
  __shared__ alignas(16) char smem[17408];   // merge only: 2 areas (one per q-set) x 8704B
  const int tid = threadIdx.x, w = tid >> 6, lane = tid & 63;  // w = kv quarter 0..3
  const int l31 = lane & 31, hi = lane >> 5;

  // ---- Q frags for both q-sets (B operand: col=q=l31, k-slots hi*8+j) ----
  const __half* qbase = Q + ((size_t)bh * 4096 + qt * 64 + l31) * 64 + hi * 8;
  half8 qf0[4], qf1[4];
  #pragma unroll
  for (int dc = 0; dc < 4; ++dc) {
    qf0[dc] = *reinterpret_cast<const half8*>(qbase + dc * 16);
    qf1[dc] = *reinterpret_cast<const half8*>(qbase + 2048 + dc * 16);  // +32 rows
  }

  const char* kfp = (const char*)KF + (size_t)bh * 524288 + (size_t)w * 131072 + lane * 16;
  const char* vfp = (const char*)VF + (size_t)bh * 524288 + (size_t)w * 131072 + lane * 16;

  f32x16 O00 = {}, O01 = {};   // q-set 0: d 0..31 / d 32..63
  f32x16 O10 = {}, O11 = {};   // q-set 1
  float m0 = -1e30f, l0 = 0.0f, m1 = -1e30f, l1 = 0.0f;

  for (int t = 0; t < 32; ++t) {
    const half8 va00 = *reinterpret_cast<const half8*>(vfp);
    const half8 va01 = *reinterpret_cast<const half8*>(vfp + 1024);
    const half8 va10 = *reinterpret_cast<const half8*>(vfp + 2048);
    const half8 va11 = *reinterpret_cast<const half8*>(vfp + 3072);
    vfp += 4096;
    const half8 kf0 = *reinterpret_cast<const half8*>(kfp);
    const half8 kf1 = *reinterpret_cast<const half8*>(kfp + 1024);
    const half8 kf2 = *reinterpret_cast<const half8*>(kfp + 2048);
    const half8 kf3 = *reinterpret_cast<const half8*>(kfp + 3072);
    kfp += 4096;
    // ---- S^T[kv][q] for both q-sets ----
    f32x16 S0 = {}, S1 = {};
    __builtin_amdgcn_s_setprio(1);
    S0 = __builtin_amdgcn_mfma_f32_32x32x16_f16(kf0, qf0[0], S0, 0, 0, 0);
    S1 = __builtin_amdgcn_mfma_f32_32x32x16_f16(kf0, qf1[0], S1, 0, 0, 0);
    S0 = __builtin_amdgcn_mfma_f32_32x32x16_f16(kf1, qf0[1], S0, 0, 0, 0);
    S1 = __builtin_amdgcn_mfma_f32_32x32x16_f16(kf1, qf1[1], S1, 0, 0, 0);
    S0 = __builtin_amdgcn_mfma_f32_32x32x16_f16(kf2, qf0[2], S0, 0, 0, 0);
    S1 = __builtin_amdgcn_mfma_f32_32x32x16_f16(kf2, qf1[2], S1, 0, 0, 0);
    S0 = __builtin_amdgcn_mfma_f32_32x32x16_f16(kf3, qf0[3], S0, 0, 0, 0);
    S1 = __builtin_amdgcn_mfma_f32_32x32x16_f16(kf3, qf1[3], S1, 0, 0, 0);
    __builtin_amdgcn_s_setprio(0);
    union U8 { unsigned u[4]; half8 h8; } p00, p01, p10, p11;
    // ---- softmax + pack, q-set 0 ----
    {
      float a0 = fmaxf(fmaxf(S0[0], S0[1]), fmaxf(S0[2], S0[3]));
      float a1 = fmaxf(fmaxf(S0[4], S0[5]), fmaxf(S0[6], S0[7]));
      float a2 = fmaxf(fmaxf(S0[8], S0[9]), fmaxf(S0[10], S0[11]));
      float a3 = fmaxf(fmaxf(S0[12], S0[13]), fmaxf(S0[14], S0[15]));
      float rmax = fmaxf(fmaxf(a0, a1), fmaxf(a2, a3));
      rmax = fmaxf(rmax, __shfl_xor(rmax, 32));
      if (!__all(rmax <= m0 + 8.0f)) {
        const float mnew = fmaxf(m0, rmax);
        const float fsc = __builtin_amdgcn_exp2f(m0 - mnew);
        l0 *= fsc;
        #pragma unroll
        for (int i = 0; i < 16; ++i) { O00[i] *= fsc; O01[i] *= fsc; }
        m0 = mnew;
      }
      #pragma unroll
      for (int i = 0; i < 16; ++i) S0[i] = __builtin_amdgcn_exp2f(S0[i] - m0);
      float s0 = (S0[0] + S0[1]) + (S0[2] + S0[3]);
      float s1 = (S0[4] + S0[5]) + (S0[6] + S0[7]);
      float s2 = (S0[8] + S0[9]) + (S0[10] + S0[11]);
      float s3 = (S0[12] + S0[13]) + (S0[14] + S0[15]);
      float rsum = (s0 + s1) + (s2 + s3);
      rsum += __shfl_xor(rsum, 32);
      l0 += rsum;
      p00.u[0] = pack_f16x2(S0[0], S0[1]);   p00.u[1] = pack_f16x2(S0[2], S0[3]);
      p00.u[2] = pack_f16x2(S0[4], S0[5]);   p00.u[3] = pack_f16x2(S0[6], S0[7]);
      p01.u[0] = pack_f16x2(S0[8], S0[9]);   p01.u[1] = pack_f16x2(S0[10], S0[11]);
      p01.u[2] = pack_f16x2(S0[12], S0[13]); p01.u[3] = pack_f16x2(S0[14], S0[15]);
    }
    // ---- softmax + pack, q-set 1 ----
    {
      float a0 = fmaxf(fmaxf(S1[0], S1[1]), fmaxf(S1[2], S1[3]));
      float a1 = fmaxf(fmaxf(S1[4], S1[5]), fmaxf(S1[6], S1[7]));
      float a2 = fmaxf(fmaxf(S1[8], S1[9]), fmaxf(S1[10], S1[11]));
      float a3 = fmaxf(fmaxf(S1[12], S1[13]), fmaxf(S1[14], S1[15]));
      float rmax = fmaxf(fmaxf(a0, a1), fmaxf(a2, a3));
      rmax = fmaxf(rmax, __shfl_xor(rmax, 32));
      if (!__all(rmax <= m1 + 8.0f)) {
        const float mnew = fmaxf(m1, rmax);
        const float fsc = __builtin_amdgcn_exp2f(m1 - mnew);
        l1 *= fsc;
        #pragma unroll
        for (int i = 0; i < 16; ++i) { O10[i] *= fsc; O11[i] *= fsc; }
        m1 = mnew;
      }
      #pragma unroll
      for (int i = 0; i < 16; ++i) S1[i] = __builtin_amdgcn_exp2f(S1[i] - m1);
      float s0 = (S1[0] + S1[1]) + (S1[2] + S1[3]);
      float s1 = (S1[4] + S1[5]) + (S1[6] + S1[7]);
      float s2 = (S1[8] + S1[9]) + (S1[10] + S1[11]);
      float s3 = (S1[12] + S1[13]) + (S1[14] + S1[15]);
      float rsum = (s0 + s1) + (s2 + s3);
      rsum += __shfl_xor(rsum, 32);
      l1 += rsum;
      p10.u[0] = pack_f16x2(S1[0], S1[1]);   p10.u[1] = pack_f16x2(S1[2], S1[3]);
      p10.u[2] = pack_f16x2(S1[4], S1[5]);   p10.u[3] = pack_f16x2(S1[6], S1[7]);
      p11.u[0] = pack_f16x2(S1[8], S1[9]);   p11.u[1] = pack_f16x2(S1[10], S1[11]);
      p11.u[2] = pack_f16x2(S1[12], S1[13]); p11.u[3] = pack_f16x2(S1[14], S1[15]);
    }
    // ---- O^T[d][q] += V^T . P^T (both q-sets share the V frags) ----
    __builtin_amdgcn_s_setprio(1);
    O00 = __builtin_amdgcn_mfma_f32_32x32x16_f16(va00, p00.h8, O00, 0, 0, 0);
    O10 = __builtin_amdgcn_mfma_f32_32x32x16_f16(va00, p10.h8, O10, 0, 0, 0);
    O00 = __builtin_amdgcn_mfma_f32_32x32x16_f16(va01, p01.h8, O00, 0, 0, 0);
    O10 = __builtin_amdgcn_mfma_f32_32x32x16_f16(va01, p11.h8, O10, 0, 0, 0);
    O01 = __builtin_amdgcn_mfma_f32_32x32x16_f16(va10, p00.h8, O01, 0, 0, 0);
    O11 = __builtin_amdgcn_mfma_f32_32x32x16_f16(va10, p10.h8, O11, 0, 0, 0);
    O01 = __builtin_amdgcn_mfma_f32_32x32x16_f16(va11, p01.h8, O01, 0, 0, 0);
    O11 = __builtin_amdgcn_mfma_f32_32x32x16_f16(va11, p11.h8, O11, 0, 0, 0);
    __builtin_amdgcn_s_setprio(0);
  }

  // ---- 3-round merge: waves 1..3 publish, wave 0 folds (exact f32) ----
  float* area0 = reinterpret_cast<float*>(smem);          // q-set 0: 2048 O + 64 m + 64 l
  float* area1 = reinterpret_cast<float*>(smem) + 2176;   // q-set 1
  for (int r = 1; r < 4; ++r) {
    __syncthreads();
    if (w == r) {
      #pragma unroll
      for (int i = 0; i < 16; ++i) {
        area0[i * 64 + lane] = O00[i];
        area0[(16 + i) * 64 + lane] = O01[i];
        area1[i * 64 + lane] = O10[i];
        area1[(16 + i) * 64 + lane] = O11[i];
      }
      area0[2048 + lane] = m0;  area0[2112 + lane] = l0;
      area1[2048 + lane] = m1;  area1[2112 + lane] = l1;
    }
    __syncthreads();
    if (w == 0) {
      {
        const float mB = area0[2048 + lane], lB = area0[2112 + lane];
        const float mx = fmaxf(m0, mB);
        const float fa = __builtin_amdgcn_exp2f(m0 - mx);
        const float fb = __builtin_amdgcn_exp2f(mB - mx);
        #pragma unroll
        for (int i = 0; i < 16; ++i) {
          O00[i] = O00[i] * fa + area0[i * 64 + lane] * fb;
          O01[i] = O01[i] * fa + area0[(16 + i) * 64 + lane] * fb;
        }
        l0 = l0 * fa + lB * fb;
        m0 = mx;
      }
      {
        const float mB = area1[2048 + lane], lB = area1[2112 + lane];
        const float mx = fmaxf(m1, mB);
        const float fa = __builtin_amdgcn_exp2f(m1 - mx);
        const float fb = __builtin_amdgcn_exp2f(mB - mx);
        #pragma unroll
        for (int i = 0; i < 16; ++i) {
          O10[i] = O10[i] * fa + area1[i * 64 + lane] * fb;
          O11[i] = O11[i] * fa + area1[(16 + i) * 64 + lane] * fb;
        }
        l1 = l1 * fa + lB * fb;
        m1 = mx;
      }
    }
  }
  // ---- normalize + store (wave 0 only) ----
  if (w == 0) {
    #pragma unroll
    for (int qs = 0; qs < 2; ++qs) {
      const f32x16& Pd0 = qs ? O10 : O00;
      const f32x16& Pd1 = qs ? O11 : O01;
      const float inv = 1.0f / (qs ? l1 : l0);
      const int qrow2 = qt * 64 + qs * 32 + l31;
      bf16* ob = Out + ((size_t)b * 4096 + qrow2) * 512 + h * 64 + hi * 4;
      #pragma unroll
      for (int db = 0; db < 2; ++db) {
        #pragma unroll
        for (int rq = 0; rq < 4; ++rq) {
          const int r = rq * 4;
          uint2 st;
          st.x = pack_bf16x2((db ? Pd1[r + 0] : Pd0[r + 0]) * inv,
                             (db ? Pd1[r + 1] : Pd0[r + 1]) * inv);
          st.y = pack_bf16x2((db ? Pd1[r + 2] : Pd0[r + 2]) * inv,
                             (db ? Pd1[r + 3] : Pd0[r + 3]) * inv);
          *reinterpret_cast<uint2*>(ob + db * 32 + rq * 8) = st;
        }
      }
    }
  }
}

// ---------------- host ----------------
extern "C" void kernel_launch(void* const* d_in, const int* in_sizes, int n_in,
                              void* d_out, int out_size, void* d_ws, size_t ws_size,
                              hipStream_t stream) {
  const float* x      = (const float*)d_in[0];
  const float* ln1_g  = (const float*)d_in[1];
  const float* ln1_b  = (const float*)d_in[2];
  const float* ln2_g  = (const float*)d_in[3];
  const float* ln2_b  = (const float*)d_in[4];
  const float* qkv_w  = (const float*)d_in[5];
  const float* qkv_b  = (const float*)d_in[6];
  const float* proj_w = (const float*)d_in[7];
  const float* proj_b = (const float*)d_in[8];
  const float* fc1_w  = (const float*)d_in[9];
  const float* fc1_b  = (const float*)d_in[10];
  const float* fc2_w  = (const float*)d_in[11];
  const float* fc2_b  = (const float*)d_in[12];

  char* ws = (char*)d_ws;
  constexpr size_t o_qkvw = 0;
  constexpr size_t o_projw = 1572864;
  constexpr size_t o_fc1w  = 2097152;
  constexpr size_t o_fc2w  = 4194304;
  constexpr size_t o_h     = 6291456;
  constexpr size_t o_qkvC  = 14680064;
  constexpr size_t o_q     = 39845888;
  constexpr size_t o_k     = 48234496;
  constexpr size_t o_vt    = 56623104;
  constexpr size_t o_attn  = 65011712;
  constexpr size_t o_x2    = 73400320;
  constexpr size_t o_fc1o  = o_qkvC;
  constexpr size_t needed  = 90177536;
  if (ws_size < needed) return;

  bf16* qkvw_bf = (bf16*)(ws + o_qkvw);
  bf16* projw_bf = (bf16*)(ws + o_projw);
  bf16* fc1w_bf = (bf16*)(ws + o_fc1w);
  bf16* fc2w_bf = (bf16*)(ws + o_fc2w);
  bf16* h     = (bf16*)(ws + o_h);
  __half* qkvC = (__half*)(ws + o_qkvC);
  __half* q    = (__half*)(ws + o_q);
  __half* kf   = (__half*)(ws + o_k);
  __half* vf   = (__half*)(ws + o_vt);
  bf16* attn  = (bf16*)(ws + o_attn);
  float* x2   = (float*)(ws + o_x2);
  bf16* fc1o  = (bf16*)(ws + o_fc1o);
  float* out  = (float*)d_out;

  cvt_all<<<3072, 256, 0, stream>>>(qkv_w, qkvw_bf, proj_w, projw_bf, fc1_w, fc1w_bf, fc2_w, fc2w_bf);

  ln_kernel<<<2048, 256, 0, stream>>>(x, ln1_g, ln1_b, h);
  gemm_bt<3><<<dim3(64, 12), 256, 0, stream>>>(h, qkvw_bf, qkv_b, nullptr, qkvC, 8192, 1536, 512);
  reshape_qkv<<<dim3(64, 16), 256, 0, stream>>>(qkvC, q, kf, vf);
  attn_kernel<<<dim3(64, 16), 256, 0, stream>>>(q, kf, vf, attn);
  gemm_bt64<2><<<dim3(128, 8), 256, 0, stream>>>(attn, projw_bf, proj_b, x, x2, 8192, 512, 512);
  ln_kernel<<<2048, 256, 0, stream>>>(x2, ln2_g, ln2_b, h);
  gemm_bt<1><<<dim3(64, 16), 256, 0, stream>>>(h, fc1w_bf, fc1_b, nullptr, fc1o, 8192, 2048, 512);
  gemm_bt64<2><<<dim3(128, 8), 256, 0, stream>>>(fc1o, fc2w_bf, fc2_b, x2, out, 8192, 512, 2048);
}

// Round 16
// 238.129 us; speedup vs baseline: 1.6516x; 1.0188x over previous
//
#include <hip/hip_runtime.h>
#include <hip/hip_bf16.h>
#include <hip/hip_fp16.h>
#include <string.h>

using bf16 = __hip_bfloat16;
typedef __attribute__((ext_vector_type(8))) short short8;       // 8 x bf16 MFMA A/B frag
typedef __attribute__((ext_vector_type(8))) _Float16 half8;     // 8 x fp16 MFMA A/B frag
typedef __attribute__((ext_vector_type(4))) float f32x4;        // 16x16 MFMA C/D frag
typedef __attribute__((ext_vector_type(16))) float f32x16;      // 32x32 MFMA C/D frag

#define GAS __attribute__((address_space(1)))
#define LAS __attribute__((address_space(3)))

__device__ __forceinline__ void gld_lds16(const void* g, void* l) {
  __builtin_amdgcn_global_load_lds((const GAS void*)g, (LAS void*)l, 16, 0, 0);
}

__device__ __forceinline__ unsigned short f2bfu(float f) {
  bf16 h = __float2bfloat16(f);
  return *reinterpret_cast<unsigned short*>(&h);
}

__device__ __forceinline__ unsigned pack_bf16x2(float lo, float hi) {
  __hip_bfloat162 v = __float22bfloat162_rn(make_float2(lo, hi));
  unsigned u;
  __builtin_memcpy(&u, &v, 4);
  return u;
}

__device__ __forceinline__ unsigned pack_f16x2(float lo, float hi) {
  __half2 v = __float22half2_rn(make_float2(lo, hi));
  unsigned u;
  __builtin_memcpy(&u, &v, 4);
  return u;
}

// ---------------- all weights f32 -> bf16 in one launch ----------------
__global__ __launch_bounds__(256) void cvt_all(const float* __restrict__ w0, bf16* __restrict__ o0,
                                               const float* __restrict__ w1, bf16* __restrict__ o1,
                                               const float* __restrict__ w2, bf16* __restrict__ o2,
                                               const float* __restrict__ w3, bf16* __restrict__ o3) {
  int i = blockIdx.x * 256 + threadIdx.x;   // f4 index, total 786432
  const float* src; bf16* dst; int off;
  if (i < 196608)      { src = w0; dst = o0; off = i; }
  else if (i < 262144) { src = w1; dst = o1; off = i - 196608; }
  else if (i < 524288) { src = w2; dst = o2; off = i - 262144; }
  else                 { src = w3; dst = o3; off = i - 524288; }
  float4 v = reinterpret_cast<const float4*>(src)[off];
  ushort4 o;
  o.x = f2bfu(v.x); o.y = f2bfu(v.y); o.z = f2bfu(v.z); o.w = f2bfu(v.w);
  reinterpret_cast<ushort4*>(dst)[off] = o;
}

// ---------------- LayerNorm (fp32 in, bf16 out), one wave per 512-row ----------------
__global__ __launch_bounds__(256) void ln_kernel(const float* __restrict__ x,
                                                 const float* __restrict__ g,
                                                 const float* __restrict__ b,
                                                 bf16* __restrict__ out) {
  const int row = blockIdx.x * 4 + (threadIdx.x >> 6);
  const int lane = threadIdx.x & 63;
  const float4* xr = reinterpret_cast<const float4*>(x + (size_t)row * 512);
  float4 v0 = xr[lane], v1 = xr[64 + lane];
  float s  = v0.x + v0.y + v0.z + v0.w + v1.x + v1.y + v1.z + v1.w;
  float s2 = v0.x*v0.x + v0.y*v0.y + v0.z*v0.z + v0.w*v0.w
           + v1.x*v1.x + v1.y*v1.y + v1.z*v1.z + v1.w*v1.w;
  #pragma unroll
  for (int d = 1; d < 64; d <<= 1) { s += __shfl_xor(s, d); s2 += __shfl_xor(s2, d); }
  const float mu = s * (1.0f / 512.0f);
  const float var = s2 * (1.0f / 512.0f) - mu * mu;
  const float rstd = rsqrtf(var + 1e-5f);
  const float4* g4 = reinterpret_cast<const float4*>(g);
  const float4* b4 = reinterpret_cast<const float4*>(b);
  float4 ga = g4[lane], gb = g4[64 + lane], ba = b4[lane], bb = b4[64 + lane];
  ushort4 o0, o1;
  o0.x = f2bfu((v0.x - mu) * rstd * ga.x + ba.x);
  o0.y = f2bfu((v0.y - mu) * rstd * ga.y + ba.y);
  o0.z = f2bfu((v0.z - mu) * rstd * ga.z + ba.z);
  o0.w = f2bfu((v0.w - mu) * rstd * ga.w + ba.w);
  o1.x = f2bfu((v1.x - mu) * rstd * gb.x + bb.x);
  o1.y = f2bfu((v1.y - mu) * rstd * gb.y + bb.y);
  o1.z = f2bfu((v1.z - mu) * rstd * gb.z + bb.z);
  o1.w = f2bfu((v1.w - mu) * rstd * gb.w + bb.w);
  ushort4* orow = reinterpret_cast<ushort4*>(out + (size_t)row * 512);
  orow[lane] = o0;
  orow[64 + lane] = o1;
}

// ---------------- GEMM 128x128: C[M,N] = A[M,K] * B[N,K]^T (+bias, epilogue) ----------------
// EPI 0: bf16 out. 1: GELU->bf16. 2: +resid(f32)->f32. 3: fp16 out.
template <int EPI>
__global__ __launch_bounds__(256) void gemm_bt(const bf16* __restrict__ A,
                                               const bf16* __restrict__ B,
                                               const float* __restrict__ bias,
                                               const float* __restrict__ resid,
                                               void* __restrict__ Cv,
                                               int M, int N, int K) {
  __shared__ bf16 As[128 * 32];
  __shared__ bf16 Bs[128 * 32];
  const int tid = threadIdx.x;
  const int lane = tid & 63, wid = tid >> 6;
  const int lr = lane & 15, lg = lane >> 4;
  const int row0 = blockIdx.x * 128, col0 = blockIdx.y * 128;
  const int wr = (wid >> 1) * 64, wc = (wid & 1) * 64;
  f32x4 acc[4][4] = {};
  const int r1 = tid >> 2,          c1 = (tid & 3) * 8;
  const int r2 = (256 + tid) >> 2,  c2 = ((256 + tid) & 3) * 8;
  for (int kt = 0; kt < K; kt += 32) {
    __syncthreads();
    gld_lds16(A + (size_t)(row0 + r1) * K + kt + c1, As + tid * 8);
    gld_lds16(A + (size_t)(row0 + r2) * K + kt + c2, As + (256 + tid) * 8);
    gld_lds16(B + (size_t)(col0 + r1) * K + kt + c1, Bs + tid * 8);
    gld_lds16(B + (size_t)(col0 + r2) * K + kt + c2, Bs + (256 + tid) * 8);
    __syncthreads();
    short8 af[4], bfr[4];
    #pragma unroll
    for (int mi = 0; mi < 4; ++mi)
      af[mi] = *reinterpret_cast<const short8*>(&As[(wr + mi * 16 + lr) * 32 + lg * 8]);
    #pragma unroll
    for (int nj = 0; nj < 4; ++nj)
      bfr[nj] = *reinterpret_cast<const short8*>(&Bs[(wc + nj * 16 + lr) * 32 + lg * 8]);
    #pragma unroll
    for (int mi = 0; mi < 4; ++mi)
      #pragma unroll
      for (int nj = 0; nj < 4; ++nj)
        acc[mi][nj] = __builtin_amdgcn_mfma_f32_16x16x32_bf16(af[mi], bfr[nj], acc[mi][nj], 0, 0, 0);
  }
  #pragma unroll
  for (int mi = 0; mi < 4; ++mi) {
    #pragma unroll
    for (int nj = 0; nj < 4; ++nj) {
      const int col = col0 + wc + nj * 16 + lr;
      const float bv = bias ? bias[col] : 0.0f;
      #pragma unroll
      for (int rg = 0; rg < 4; ++rg) {
        const int row = row0 + wr + mi * 16 + lg * 4 + rg;
        float v = acc[mi][nj][rg] + bv;
        if constexpr (EPI == 1) v = 0.5f * v * (1.0f + erff(v * 0.70710678118654752f));
        if constexpr (EPI == 2) {
          reinterpret_cast<float*>(Cv)[(size_t)row * N + col] = v + resid[(size_t)row * N + col];
        } else if constexpr (EPI == 3) {
          reinterpret_cast<__half*>(Cv)[(size_t)row * N + col] = __float2half(v);
        } else {
          reinterpret_cast<bf16*>(Cv)[(size_t)row * N + col] = __float2bfloat16(v);
        }
      }
    }
  }
}

// ---------------- GEMM 64x64 (BK=64, swizzled LDS): for N=512 GEMMs, 1024-block grids ----------------
template <int EPI>
__global__ __launch_bounds__(256) void gemm_bt64(const bf16* __restrict__ A,
                                                 const bf16* __restrict__ B,
                                                 const float* __restrict__ bias,
                                                 const float* __restrict__ resid,
                                                 void* __restrict__ Cv,
                                                 int M, int N, int K) {
  __shared__ bf16 As[64 * 64];   // [64 rows][128B], XOR-swizzled
  __shared__ bf16 Bs[64 * 64];
  const int tid = threadIdx.x;
  const int lane = tid & 63, wid = tid >> 6;
  const int lr = lane & 15, lg = lane >> 4;
  const int row0 = blockIdx.x * 64, col0 = blockIdx.y * 64;
  const int wr = (wid >> 1) * 32, wc = (wid & 1) * 32;
  f32x4 acc[2][2] = {};
  const int xsw = (lr & 7) << 4;
  const int fb0 = lr * 128 + ((lg * 16) ^ xsw);
  const int fb1 = lr * 128 + ((64 + lg * 16) ^ xsw);
  const int ph0 = tid * 16, ph1 = (256 + tid) * 16;
  const int r0 = ph0 >> 7, r1 = ph1 >> 7;
  const int lb0 = ph0 ^ ((r0 & 7) << 4), lb1 = ph1 ^ ((r1 & 7) << 4);
  const char* Ab0 = (const char*)A + (size_t)(row0 + r0) * K * 2 + (lb0 & 127);
  const char* Ab1 = (const char*)A + (size_t)(row0 + r1) * K * 2 + (lb1 & 127);
  const char* Bb0 = (const char*)B + (size_t)(col0 + r0) * K * 2 + (lb0 & 127);
  const char* Bb1 = (const char*)B + (size_t)(col0 + r1) * K * 2 + (lb1 & 127);
  for (int kt = 0; kt < K; kt += 64) {
    __syncthreads();
    gld_lds16(Ab0 + kt * 2, (char*)As + ph0);
    gld_lds16(Ab1 + kt * 2, (char*)As + ph1);
    gld_lds16(Bb0 + kt * 2, (char*)Bs + ph0);
    gld_lds16(Bb1 + kt * 2, (char*)Bs + ph1);
    __syncthreads();
    short8 af0[2], af1[2], bf0[2], bf1[2];
    #pragma unroll
    for (int mi = 0; mi < 2; ++mi) {
      af0[mi] = *reinterpret_cast<const short8*>((const char*)As + (wr + mi * 16) * 128 + fb0);
      af1[mi] = *reinterpret_cast<const short8*>((const char*)As + (wr + mi * 16) * 128 + fb1);
    }
    #pragma unroll
    for (int nj = 0; nj < 2; ++nj) {
      bf0[nj] = *reinterpret_cast<const short8*>((const char*)Bs + (wc + nj * 16) * 128 + fb0);
      bf1[nj] = *reinterpret_cast<const short8*>((const char*)Bs + (wc + nj * 16) * 128 + fb1);
    }
    #pragma unroll
    for (int mi = 0; mi < 2; ++mi)
      #pragma unroll
      for (int nj = 0; nj < 2; ++nj) {
        acc[mi][nj] = __builtin_amdgcn_mfma_f32_16x16x32_bf16(af0[mi], bf0[nj], acc[mi][nj], 0, 0, 0);
        acc[mi][nj] = __builtin_amdgcn_mfma_f32_16x16x32_bf16(af1[mi], bf1[nj], acc[mi][nj], 0, 0, 0);
      }
  }
  #pragma unroll
  for (int mi = 0; mi < 2; ++mi) {
    #pragma unroll
    for (int nj = 0; nj < 2; ++nj) {
      const int col = col0 + wc + nj * 16 + lr;
      const float bv = bias ? bias[col] : 0.0f;
      #pragma unroll
      for (int rg = 0; rg < 4; ++rg) {
        const int row = row0 + wr + mi * 16 + lg * 4 + rg;
        float v = acc[mi][nj][rg] + bv;
        if constexpr (EPI == 1) v = 0.5f * v * (1.0f + erff(v * 0.70710678118654752f));
        if constexpr (EPI == 2) {
          reinterpret_cast<float*>(Cv)[(size_t)row * N + col] = v + resid[(size_t)row * N + col];
        } else {
          reinterpret_cast<bf16*>(Cv)[(size_t)row * N + col] = __float2bfloat16(v);
        }
      }
    }
  }
}

// ---------------- reshape QKV (fp16 in): q [BH,N,64] (scaled); K,V -> 32x32 A-frag-major fp16 ----------------
// KF[bh][t32][dc(4)][lane l][j]: = K[kv = t32*32 + (l&31)][d = dc*16 + (l>>5)*8 + j]
// VF[bh][t32][db(2)][c(2)][lane l][j]: = V[n = t32*32 + c*16 + 4*(l>>5) + (j&3) + 8*(j>>2)][d = db*32 + (l&31)]
__global__ __launch_bounds__(256) void reshape_qkv(const __half* __restrict__ C,
                                                   __half* __restrict__ q,
                                                   __half* __restrict__ KF,
                                                   __half* __restrict__ VF) {
  const int nt = blockIdx.x;   // 64-row tile
  const int bh = blockIdx.y;
  const int b = bh >> 3, h = bh & 7;
  __shared__ alignas(16) __half vs[64][72];  // [d][n] transposed tile
  const int tid = threadIdx.x;
  const float qs = 0.125f * 1.44269504088896340736f;
  #pragma unroll
  for (int i = 0; i < 16; ++i) {
    const int idx = i * 256 + tid;
    const int rr = idx >> 6, c = idx & 63;
    const size_t crow = ((size_t)b * 4096 + nt * 64 + rr) * 1536;
    const size_t onb = ((size_t)bh * 4096 + nt * 64 + rr) * 64 + c;
    q[onb] = __float2half(__half2float(C[crow + h * 64 + c]) * qs);
    vs[c][rr] = C[crow + 1024 + h * 64 + c];   // transposed: vs[d][n]
  }
  // K frag-major (contiguous 16B source chunks, no LDS needed)
  #pragma unroll
  for (int i = 0; i < 2; ++i) {
    const int s = i * 256 + tid;               // 0..511
    const int half_ = s >> 8, dc = (s >> 6) & 3, l = s & 63;
    const int l31 = l & 31, hi2 = l >> 5;
    const __half* src = C + ((size_t)b * 4096 + nt * 64 + half_ * 32 + l31) * 1536
                          + 512 + h * 64 + dc * 16 + hi2 * 8;
    __half* dst = KF + ((size_t)bh * 128 + nt * 2 + half_) * 2048 + dc * 512 + (size_t)l * 8;
    *reinterpret_cast<short8*>(dst) = *reinterpret_cast<const short8*>(src);
  }
  __syncthreads();
  #pragma unroll
  for (int i = 0; i < 2; ++i) {
    const int s = i * 256 + tid;               // 0..511
    const int half_ = (s >> 8) & 1, db = (s >> 7) & 1, c = (s >> 6) & 1, l = s & 63;
    const int d = db * 32 + (l & 31);
    const int n0 = half_ * 32 + c * 16 + ((l >> 5) << 2);
    const short4 lo = *reinterpret_cast<const short4*>(&vs[d][n0]);
    const short4 hi = *reinterpret_cast<const short4*>(&vs[d][n0 + 8]);
    short8 v;
    v[0] = lo.x; v[1] = lo.y; v[2] = lo.z; v[3] = lo.w;
    v[4] = hi.x; v[5] = hi.y; v[6] = hi.z; v[7] = hi.w;
    __half* dst = VF + ((size_t)bh * 128 + nt * 2 + half_) * 2048 + (db * 2 + c) * 512 + (size_t)l * 8;
    *reinterpret_cast<short8*>(dst) = v;
  }
}

// ---------------- flash attention: fp16 32x32 MFMA, 64 q/wave (2 B-operand sets), barrier-free loop ----------------
// Block = 4 waves: qg = w>>1 (which 64-q slab), kvh = w&1 (kv half). Split-KV merge per q-set at end.
// R16: XCD-aware block swizzle — XCD k handles heads {2k,2k+1}; per-XCD KV working set 2MB (L2-resident).
__global__ __launch_bounds__(256, 2) void attn_kernel(const __half* __restrict__ Q,
                                                      const __half* __restrict__ KF,
                                                      const __half* __restrict__ VF,
                                                      bf16* __restrict__ Out) {
  // bijective swizzle over 512 blocks: bid -> swz = (bid%8)*64 + bid/8
  const int bid = blockIdx.y * 32 + blockIdx.x;
  const int swz = (bid & 7) * 64 + (bid >> 3);
  const int qt = swz & 31;     // 0..31 (128 q rows per block)
  const int bh = swz >> 5;     // 0..15
  const int b = bh >> 3, h = bh & 7;
  __shared__ alignas(16) char smem[17408];   // merge only (one q-set at a time)
  const int tid = threadIdx.x, w = tid >> 6, lane = tid & 63;
  const int qg = w >> 1, kvh = w & 1;
  const int l31 = lane & 31, hi = lane >> 5;

  // ---- Q frags for both q-sets (B operand: col=q=l31, k-slots hi*8+j) ----
  const __half* qbase = Q + ((size_t)bh * 4096 + qt * 128 + qg * 64 + l31) * 64 + hi * 8;
  half8 qf0[4], qf1[4];
  #pragma unroll
  for (int dc = 0; dc < 4; ++dc) {
    qf0[dc] = *reinterpret_cast<const half8*>(qbase + dc * 16);
    qf1[dc] = *reinterpret_cast<const half8*>(qbase + 2048 + dc * 16);  // +32 rows
  }

  const char* kfp = (const char*)KF + (size_t)bh * 524288 + (size_t)kvh * 262144 + lane * 16;
  const char* vfp = (const char*)VF + (size_t)bh * 524288 + (size_t)kvh * 262144 + lane * 16;

  f32x16 O00 = {}, O01 = {};   // q-set 0: d 0..31 / d 32..63
  f32x16 O10 = {}, O11 = {};   // q-set 1
  float m0 = -1e30f, l0 = 0.0f, m1 = -1e30f, l1 = 0.0f;

  for (int t = 0; t < 64; ++t) {
    const half8 va00 = *reinterpret_cast<const half8*>(vfp);
    const half8 va01 = *reinterpret_cast<const half8*>(vfp + 1024);
    const half8 va10 = *reinterpret_cast<const half8*>(vfp + 2048);
    const half8 va11 = *reinterpret_cast<const half8*>(vfp + 3072);
    vfp += 4096;
    const half8 kf0 = *reinterpret_cast<const half8*>(kfp);
    const half8 kf1 = *reinterpret_cast<const half8*>(kfp + 1024);
    const half8 kf2 = *reinterpret_cast<const half8*>(kfp + 2048);
    const half8 kf3 = *reinterpret_cast<const half8*>(kfp + 3072);
    kfp += 4096;
    // ---- S^T[kv][q] for both q-sets ----
    f32x16 S0 = {}, S1 = {};
    __builtin_amdgcn_s_setprio(1);
    S0 = __builtin_amdgcn_mfma_f32_32x32x16_f16(kf0, qf0[0], S0, 0, 0, 0);
    S1 = __builtin_amdgcn_mfma_f32_32x32x16_f16(kf0, qf1[0], S1, 0, 0, 0);
    S0 = __builtin_amdgcn_mfma_f32_32x32x16_f16(kf1, qf0[1], S0, 0, 0, 0);
    S1 = __builtin_amdgcn_mfma_f32_32x32x16_f16(kf1, qf1[1], S1, 0, 0, 0);
    S0 = __builtin_amdgcn_mfma_f32_32x32x16_f16(kf2, qf0[2], S0, 0, 0, 0);
    S1 = __builtin_amdgcn_mfma_f32_32x32x16_f16(kf2, qf1[2], S1, 0, 0, 0);
    S0 = __builtin_amdgcn_mfma_f32_32x32x16_f16(kf3, qf0[3], S0, 0, 0, 0);
    S1 = __builtin_amdgcn_mfma_f32_32x32x16_f16(kf3, qf1[3], S1, 0, 0, 0);
    __builtin_amdgcn_s_setprio(0);
    union U8 { unsigned u[4]; half8 h8; } p00, p01, p10, p11;
    // ---- softmax + pack, q-set 0 ----
    {
      float a0 = fmaxf(fmaxf(S0[0], S0[1]), fmaxf(S0[2], S0[3]));
      float a1 = fmaxf(fmaxf(S0[4], S0[5]), fmaxf(S0[6], S0[7]));
      float a2 = fmaxf(fmaxf(S0[8], S0[9]), fmaxf(S0[10], S0[11]));
      float a3 = fmaxf(fmaxf(S0[12], S0[13]), fmaxf(S0[14], S0[15]));
      float rmax = fmaxf(fmaxf(a0, a1), fmaxf(a2, a3));
      rmax = fmaxf(rmax, __shfl_xor(rmax, 32));
      if (!__all(rmax <= m0 + 8.0f)) {
        const float mnew = fmaxf(m0, rmax);
        const float fsc = __builtin_amdgcn_exp2f(m0 - mnew);
        l0 *= fsc;
        #pragma unroll
        for (int i = 0; i < 16; ++i) { O00[i] *= fsc; O01[i] *= fsc; }
        m0 = mnew;
      }
      #pragma unroll
      for (int i = 0; i < 16; ++i) S0[i] = __builtin_amdgcn_exp2f(S0[i] - m0);
      float s0 = (S0[0] + S0[1]) + (S0[2] + S0[3]);
      float s1 = (S0[4] + S0[5]) + (S0[6] + S0[7]);
      float s2 = (S0[8] + S0[9]) + (S0[10] + S0[11]);
      float s3 = (S0[12] + S0[13]) + (S0[14] + S0[15]);
      float rsum = (s0 + s1) + (s2 + s3);
      rsum += __shfl_xor(rsum, 32);
      l0 += rsum;
      p00.u[0] = pack_f16x2(S0[0], S0[1]);   p00.u[1] = pack_f16x2(S0[2], S0[3]);
      p00.u[2] = pack_f16x2(S0[4], S0[5]);   p00.u[3] = pack_f16x2(S0[6], S0[7]);
      p01.u[0] = pack_f16x2(S0[8], S0[9]);   p01.u[1] = pack_f16x2(S0[10], S0[11]);
      p01.u[2] = pack_f16x2(S0[12], S0[13]); p01.u[3] = pack_f16x2(S0[14], S0[15]);
    }
    // ---- softmax + pack, q-set 1 ----
    {
      float a0 = fmaxf(fmaxf(S1[0], S1[1]), fmaxf(S1[2], S1[3]));
      float a1 = fmaxf(fmaxf(S1[4], S1[5]), fmaxf(S1[6], S1[7]));
      float a2 = fmaxf(fmaxf(S1[8], S1[9]), fmaxf(S1[10], S1[11]));
      float a3 = fmaxf(fmaxf(S1[12], S1[13]), fmaxf(S1[14], S1[15]));
      float rmax = fmaxf(fmaxf(a0, a1), fmaxf(a2, a3));
      rmax = fmaxf(rmax, __shfl_xor(rmax, 32));
      if (!__all(rmax <= m1 + 8.0f)) {
        const float mnew = fmaxf(m1, rmax);
        const float fsc = __builtin_amdgcn_exp2f(m1 - mnew);
        l1 *= fsc;
        #pragma unroll
        for (int i = 0; i < 16; ++i) { O10[i] *= fsc; O11[i] *= fsc; }
        m1 = mnew;
      }
      #pragma unroll
      for (int i = 0; i < 16; ++i) S1[i] = __builtin_amdgcn_exp2f(S1[i] - m1);
      float s0 = (S1[0] + S1[1]) + (S1[2] + S1[3]);
      float s1 = (S1[4] + S1[5]) + (S1[6] + S1[7]);
      float s2 = (S1[8] + S1[9]) + (S1[10] + S1[11]);
      float s3 = (S1[12] + S1[13]) + (S1[14] + S1[15]);
      float rsum = (s0 + s1) + (s2 + s3);
      rsum += __shfl_xor(rsum, 32);
      l1 += rsum;
      p10.u[0] = pack_f16x2(S1[0], S1[1]);   p10.u[1] = pack_f16x2(S1[2], S1[3]);
      p10.u[2] = pack_f16x2(S1[4], S1[5]);   p10.u[3] = pack_f16x2(S1[6], S1[7]);
      p11.u[0] = pack_f16x2(S1[8], S1[9]);   p11.u[1] = pack_f16x2(S1[10], S1[11]);
      p11.u[2] = pack_f16x2(S1[12], S1[13]); p11.u[3] = pack_f16x2(S1[14], S1[15]);
    }
    // ---- O^T[d][q] += V^T . P^T (both q-sets share the V frags) ----
    __builtin_amdgcn_s_setprio(1);
    O00 = __builtin_amdgcn_mfma_f32_32x32x16_f16(va00, p00.h8, O00, 0, 0, 0);
    O10 = __builtin_amdgcn_mfma_f32_32x32x16_f16(va00, p10.h8, O10, 0, 0, 0);
    O00 = __builtin_amdgcn_mfma_f32_32x32x16_f16(va01, p01.h8, O00, 0, 0, 0);
    O10 = __builtin_amdgcn_mfma_f32_32x32x16_f16(va01, p11.h8, O10, 0, 0, 0);
    O01 = __builtin_amdgcn_mfma_f32_32x32x16_f16(va10, p00.h8, O01, 0, 0, 0);
    O11 = __builtin_amdgcn_mfma_f32_32x32x16_f16(va10, p10.h8, O11, 0, 0, 0);
    O01 = __builtin_amdgcn_mfma_f32_32x32x16_f16(va11, p01.h8, O01, 0, 0, 0);
    O11 = __builtin_amdgcn_mfma_f32_32x32x16_f16(va11, p11.h8, O11, 0, 0, 0);
    __builtin_amdgcn_s_setprio(0);
  }

  // ---- split-KV merge, one q-set at a time (reuses the same LDS area) ----
  float* area = reinterpret_cast<float*>(smem) + qg * 2176;  // 2048 O + 64 m + 64 l floats
  #pragma unroll
  for (int qs = 0; qs < 2; ++qs) {
    const f32x16& Pd0 = qs ? O10 : O00;
    const f32x16& Pd1 = qs ? O11 : O01;
    const float mw = qs ? m1 : m0;
    const float lw = qs ? l1 : l0;
    __syncthreads();
    if (kvh) {
      #pragma unroll
      for (int r = 0; r < 16; ++r) {
        area[r * 64 + lane] = Pd0[r];
        area[(16 + r) * 64 + lane] = Pd1[r];
      }
      area[2048 + lane] = mw;
      area[2112 + lane] = lw;
    }
    __syncthreads();
    if (!kvh) {
      const float mB = area[2048 + lane], lB = area[2112 + lane];
      const float mx = fmaxf(mw, mB);
      const float fa = __builtin_amdgcn_exp2f(mw - mx);
      const float fb = __builtin_amdgcn_exp2f(mB - mx);
      const float inv = 1.0f / (lw * fa + lB * fb);
      const int qrow2 = qt * 128 + qg * 64 + qs * 32 + l31;
      bf16* ob = Out + ((size_t)b * 4096 + qrow2) * 512 + h * 64 + hi * 4;
      #pragma unroll
      for (int db = 0; db < 2; ++db) {
        #pragma unroll
        for (int rq = 0; rq < 4; ++rq) {
          const int r = rq * 4;
          float v0 = ((db ? Pd1[r + 0] : Pd0[r + 0]) * fa + area[(db * 16 + r + 0) * 64 + lane] * fb) * inv;
          float v1 = ((db ? Pd1[r + 1] : Pd0[r + 1]) * fa + area[(db * 16 + r + 1) * 64 + lane] * fb) * inv;
          float v2 = ((db ? Pd1[r + 2] : Pd0[r + 2]) * fa + area[(db * 16 + r + 2) * 64 + lane] * fb) * inv;
          float v3 = ((db ? Pd1[r + 3] : Pd0[r + 3]) * fa + area[(db * 16 + r + 3) * 64 + lane] * fb) * inv;
          uint2 st;
          st.x = pack_bf16x2(v0, v1);
          st.y = pack_bf16x2(v2, v3);
          *reinterpret_cast<uint2*>(ob + db * 32 + rq * 8) = st;
        }
      }
    }
  }
}

// ---------------- host ----------------
extern "C" void kernel_launch(void* const* d_in, const int* in_sizes, int n_in,
                              void* d_out, int out_size, void* d_ws, size_t ws_size,
                              hipStream_t stream) {
  const float* x      = (const float*)d_in[0];
  const float* ln1_g  = (const float*)d_in[1];
  const float* ln1_b  = (const float*)d_in[2];
  const float* ln2_g  = (const float*)d_in[3];
  const float* ln2_b  = (const float*)d_in[4];
  const float* qkv_w  = (const float*)d_in[5];
  const float* qkv_b  = (const float*)d_in[6];
  const float* proj_w = (const float*)d_in[7];
  const float* proj_b = (const float*)d_in[8];
  const float* fc1_w  = (const float*)d_in[9];
  const float* fc1_b  = (const float*)d_in[10];
  const float* fc2_w  = (const float*)d_in[11];
  const float* fc2_b  = (const float*)d_in[12];

  char* ws = (char*)d_ws;
  constexpr size_t o_qkvw = 0;
  constexpr size_t o_projw = 1572864;
  constexpr size_t o_fc1w  = 2097152;
  constexpr size_t o_fc2w  = 4194304;
  constexpr size_t o_h     = 6291456;
  constexpr size_t o_qkvC  = 14680064;
  constexpr size_t o_q     = 39845888;
  constexpr size_t o_k     = 48234496;
  constexpr size_t o_vt    = 56623104;
  constexpr size_t o_attn  = 65011712;
  constexpr size_t o_x2    = 73400320;
  constexpr size_t o_fc1o  = o_qkvC;
  constexpr size_t needed  = 90177536;
  if (ws_size < needed) return;

  bf16* qkvw_bf = (bf16*)(ws + o_qkvw);
  bf16* projw_bf = (bf16*)(ws + o_projw);
  bf16* fc1w_bf = (bf16*)(ws + o_fc1w);
  bf16* fc2w_bf = (bf16*)(ws + o_fc2w);
  bf16* h     = (bf16*)(ws + o_h);
  __half* qkvC = (__half*)(ws + o_qkvC);
  __half* q    = (__half*)(ws + o_q);
  __half* kf   = (__half*)(ws + o_k);
  __half* vf   = (__half*)(ws + o_vt);
  bf16* attn  = (bf16*)(ws + o_attn);
  float* x2   = (float*)(ws + o_x2);
  bf16* fc1o  = (bf16*)(ws + o_fc1o);
  float* out  = (float*)d_out;

  cvt_all<<<3072, 256, 0, stream>>>(qkv_w, qkvw_bf, proj_w, projw_bf, fc1_w, fc1w_bf, fc2_w, fc2w_bf);

  ln_kernel<<<2048, 256, 0, stream>>>(x, ln1_g, ln1_b, h);
  gemm_bt<3><<<dim3(64, 12), 256, 0, stream>>>(h, qkvw_bf, qkv_b, nullptr, qkvC, 8192, 1536, 512);
  reshape_qkv<<<dim3(64, 16), 256, 0, stream>>>(qkvC, q, kf, vf);
  attn_kernel<<<dim3(32, 16), 256, 0, stream>>>(q, kf, vf, attn);
  gemm_bt64<2><<<dim3(128, 8), 256, 0, stream>>>(attn, projw_bf, proj_b, x, x2, 8192, 512, 512);
  ln_kernel<<<2048, 256, 0, stream>>>(x2, ln2_g, ln2_b, h);
  gemm_bt<1><<<dim3(64, 16), 256, 0, stream>>>(h, fc1w_bf, fc1_b, nullptr, fc1o, 8192, 2048, 512);
  gemm_bt64<2><<<dim3(128, 8), 256, 0, stream>>>(fc1o, fc2w_bf, fc2_b, x2, out, 8192, 512, 2048);
}

// Round 17
// 237.503 us; speedup vs baseline: 1.6559x; 1.0026x over previous
//
#include <hip/hip_runtime.h>
#include <hip/hip_bf16.h>
#include <hip/hip_fp16.h>
#include <string.h>

using bf16 = __hip_bfloat16;
typedef __attribute__((ext_vector_type(8))) short short8;       // 8 x bf16 MFMA A/B frag
typedef __attribute__((ext_vector_type(8))) _Float16 half8;     // 8 x fp16 MFMA A/B frag
typedef __attribute__((ext_vector_type(4))) float f32x4;        // 16x16 MFMA C/D frag
typedef __attribute__((ext_vector_type(16))) float f32x16;      // 32x32 MFMA C/D frag

#define GAS __attribute__((address_space(1)))
#define LAS __attribute__((address_space(3)))

__device__ __forceinline__ void gld_lds16(const void* g, void* l) {
  __builtin_amdgcn_global_load_lds((const GAS void*)g, (LAS void*)l, 16, 0, 0);
}

__device__ __forceinline__ unsigned short f2bfu(float f) {
  bf16 h = __float2bfloat16(f);
  return *reinterpret_cast<unsigned short*>(&h);
}

__device__ __forceinline__ unsigned pack_bf16x2(float lo, float hi) {
  __hip_bfloat162 v = __float22bfloat162_rn(make_float2(lo, hi));
  unsigned u;
  __builtin_memcpy(&u, &v, 4);
  return u;
}

__device__ __forceinline__ unsigned pack_f16x2(float lo, float hi) {
  __half2 v = __float22half2_rn(make_float2(lo, hi));
  unsigned u;
  __builtin_memcpy(&u, &v, 4);
  return u;
}

// XCD-aware bijective remap: XCD k owns row-chunk k (all col-tiles). Requires grid % 8 == 0.
__device__ __forceinline__ void xcd_tile_remap(int& bx, int& by) {
  const int bidl = blockIdx.y * gridDim.x + blockIdx.x;
  const int xcd = bidl & 7;
  const int j = bidl >> 3;
  const int R = gridDim.x >> 3;   // row-tiles per XCD chunk
  bx = xcd * R + (j % R);
  by = j / R;
}

// ---------------- all weights f32 -> bf16 in one launch ----------------
__global__ __launch_bounds__(256) void cvt_all(const float* __restrict__ w0, bf16* __restrict__ o0,
                                               const float* __restrict__ w1, bf16* __restrict__ o1,
                                               const float* __restrict__ w2, bf16* __restrict__ o2,
                                               const float* __restrict__ w3, bf16* __restrict__ o3) {
  int i = blockIdx.x * 256 + threadIdx.x;   // f4 index, total 786432
  const float* src; bf16* dst; int off;
  if (i < 196608)      { src = w0; dst = o0; off = i; }
  else if (i < 262144) { src = w1; dst = o1; off = i - 196608; }
  else if (i < 524288) { src = w2; dst = o2; off = i - 262144; }
  else                 { src = w3; dst = o3; off = i - 524288; }
  float4 v = reinterpret_cast<const float4*>(src)[off];
  ushort4 o;
  o.x = f2bfu(v.x); o.y = f2bfu(v.y); o.z = f2bfu(v.z); o.w = f2bfu(v.w);
  reinterpret_cast<ushort4*>(dst)[off] = o;
}

// ---------------- LayerNorm (fp32 in, bf16 out), one wave per 512-row ----------------
__global__ __launch_bounds__(256) void ln_kernel(const float* __restrict__ x,
                                                 const float* __restrict__ g,
                                                 const float* __restrict__ b,
                                                 bf16* __restrict__ out) {
  const int row = blockIdx.x * 4 + (threadIdx.x >> 6);
  const int lane = threadIdx.x & 63;
  const float4* xr = reinterpret_cast<const float4*>(x + (size_t)row * 512);
  float4 v0 = xr[lane], v1 = xr[64 + lane];
  float s  = v0.x + v0.y + v0.z + v0.w + v1.x + v1.y + v1.z + v1.w;
  float s2 = v0.x*v0.x + v0.y*v0.y + v0.z*v0.z + v0.w*v0.w
           + v1.x*v1.x + v1.y*v1.y + v1.z*v1.z + v1.w*v1.w;
  #pragma unroll
  for (int d = 1; d < 64; d <<= 1) { s += __shfl_xor(s, d); s2 += __shfl_xor(s2, d); }
  const float mu = s * (1.0f / 512.0f);
  const float var = s2 * (1.0f / 512.0f) - mu * mu;
  const float rstd = rsqrtf(var + 1e-5f);
  const float4* g4 = reinterpret_cast<const float4*>(g);
  const float4* b4 = reinterpret_cast<const float4*>(b);
  float4 ga = g4[lane], gb = g4[64 + lane], ba = b4[lane], bb = b4[64 + lane];
  ushort4 o0, o1;
  o0.x = f2bfu((v0.x - mu) * rstd * ga.x + ba.x);
  o0.y = f2bfu((v0.y - mu) * rstd * ga.y + ba.y);
  o0.z = f2bfu((v0.z - mu) * rstd * ga.z + ba.z);
  o0.w = f2bfu((v0.w - mu) * rstd * ga.w + ba.w);
  o1.x = f2bfu((v1.x - mu) * rstd * gb.x + bb.x);
  o1.y = f2bfu((v1.y - mu) * rstd * gb.y + bb.y);
  o1.z = f2bfu((v1.z - mu) * rstd * gb.z + bb.z);
  o1.w = f2bfu((v1.w - mu) * rstd * gb.w + bb.w);
  ushort4* orow = reinterpret_cast<ushort4*>(out + (size_t)row * 512);
  orow[lane] = o0;
  orow[64 + lane] = o1;
}

// ---------------- GEMM 128x128: C[M,N] = A[M,K] * B[N,K]^T (+bias, epilogue), XCD-swizzled ----------------
// EPI 0: bf16 out. 1: GELU->bf16. 2: +resid(f32)->f32. 3: fp16 out.
template <int EPI>
__global__ __launch_bounds__(256) void gemm_bt(const bf16* __restrict__ A,
                                               const bf16* __restrict__ B,
                                               const float* __restrict__ bias,
                                               const float* __restrict__ resid,
                                               void* __restrict__ Cv,
                                               int M, int N, int K) {
  __shared__ bf16 As[128 * 32];
  __shared__ bf16 Bs[128 * 32];
  const int tid = threadIdx.x;
  const int lane = tid & 63, wid = tid >> 6;
  const int lr = lane & 15, lg = lane >> 4;
  int bx, by;
  xcd_tile_remap(bx, by);
  const int row0 = bx * 128, col0 = by * 128;
  const int wr = (wid >> 1) * 64, wc = (wid & 1) * 64;
  f32x4 acc[4][4] = {};
  const int r1 = tid >> 2,          c1 = (tid & 3) * 8;
  const int r2 = (256 + tid) >> 2,  c2 = ((256 + tid) & 3) * 8;
  for (int kt = 0; kt < K; kt += 32) {
    __syncthreads();
    gld_lds16(A + (size_t)(row0 + r1) * K + kt + c1, As + tid * 8);
    gld_lds16(A + (size_t)(row0 + r2) * K + kt + c2, As + (256 + tid) * 8);
    gld_lds16(B + (size_t)(col0 + r1) * K + kt + c1, Bs + tid * 8);
    gld_lds16(B + (size_t)(col0 + r2) * K + kt + c2, Bs + (256 + tid) * 8);
    __syncthreads();
    short8 af[4], bfr[4];
    #pragma unroll
    for (int mi = 0; mi < 4; ++mi)
      af[mi] = *reinterpret_cast<const short8*>(&As[(wr + mi * 16 + lr) * 32 + lg * 8]);
    #pragma unroll
    for (int nj = 0; nj < 4; ++nj)
      bfr[nj] = *reinterpret_cast<const short8*>(&Bs[(wc + nj * 16 + lr) * 32 + lg * 8]);
    #pragma unroll
    for (int mi = 0; mi < 4; ++mi)
      #pragma unroll
      for (int nj = 0; nj < 4; ++nj)
        acc[mi][nj] = __builtin_amdgcn_mfma_f32_16x16x32_bf16(af[mi], bfr[nj], acc[mi][nj], 0, 0, 0);
  }
  #pragma unroll
  for (int mi = 0; mi < 4; ++mi) {
    #pragma unroll
    for (int nj = 0; nj < 4; ++nj) {
      const int col = col0 + wc + nj * 16 + lr;
      const float bv = bias ? bias[col] : 0.0f;
      #pragma unroll
      for (int rg = 0; rg < 4; ++rg) {
        const int row = row0 + wr + mi * 16 + lg * 4 + rg;
        float v = acc[mi][nj][rg] + bv;
        if constexpr (EPI == 1) v = 0.5f * v * (1.0f + erff(v * 0.70710678118654752f));
        if constexpr (EPI == 2) {
          reinterpret_cast<float*>(Cv)[(size_t)row * N + col] = v + resid[(size_t)row * N + col];
        } else if constexpr (EPI == 3) {
          reinterpret_cast<__half*>(Cv)[(size_t)row * N + col] = __float2half(v);
        } else {
          reinterpret_cast<bf16*>(Cv)[(size_t)row * N + col] = __float2bfloat16(v);
        }
      }
    }
  }
}

// ---------------- GEMM 64x64 (BK=64, swizzled LDS), XCD-swizzled: for N=512 GEMMs ----------------
template <int EPI>
__global__ __launch_bounds__(256) void gemm_bt64(const bf16* __restrict__ A,
                                                 const bf16* __restrict__ B,
                                                 const float* __restrict__ bias,
                                                 const float* __restrict__ resid,
                                                 void* __restrict__ Cv,
                                                 int M, int N, int K) {
  __shared__ bf16 As[64 * 64];   // [64 rows][128B], XOR-swizzled
  __shared__ bf16 Bs[64 * 64];
  const int tid = threadIdx.x;
  const int lane = tid & 63, wid = tid >> 6;
  const int lr = lane & 15, lg = lane >> 4;
  int bx, by;
  xcd_tile_remap(bx, by);
  const int row0 = bx * 64, col0 = by * 64;
  const int wr = (wid >> 1) * 32, wc = (wid & 1) * 32;
  f32x4 acc[2][2] = {};
  const int xsw = (lr & 7) << 4;
  const int fb0 = lr * 128 + ((lg * 16) ^ xsw);
  const int fb1 = lr * 128 + ((64 + lg * 16) ^ xsw);
  const int ph0 = tid * 16, ph1 = (256 + tid) * 16;
  const int r0 = ph0 >> 7, r1 = ph1 >> 7;
  const int lb0 = ph0 ^ ((r0 & 7) << 4), lb1 = ph1 ^ ((r1 & 7) << 4);
  const char* Ab0 = (const char*)A + (size_t)(row0 + r0) * K * 2 + (lb0 & 127);
  const char* Ab1 = (const char*)A + (size_t)(row0 + r1) * K * 2 + (lb1 & 127);
  const char* Bb0 = (const char*)B + (size_t)(col0 + r0) * K * 2 + (lb0 & 127);
  const char* Bb1 = (const char*)B + (size_t)(col0 + r1) * K * 2 + (lb1 & 127);
  for (int kt = 0; kt < K; kt += 64) {
    __syncthreads();
    gld_lds16(Ab0 + kt * 2, (char*)As + ph0);
    gld_lds16(Ab1 + kt * 2, (char*)As + ph1);
    gld_lds16(Bb0 + kt * 2, (char*)Bs + ph0);
    gld_lds16(Bb1 + kt * 2, (char*)Bs + ph1);
    __syncthreads();
    short8 af0[2], af1[2], bf0[2], bf1[2];
    #pragma unroll
    for (int mi = 0; mi < 2; ++mi) {
      af0[mi] = *reinterpret_cast<const short8*>((const char*)As + (wr + mi * 16) * 128 + fb0);
      af1[mi] = *reinterpret_cast<const short8*>((const char*)As + (wr + mi * 16) * 128 + fb1);
    }
    #pragma unroll
    for (int nj = 0; nj < 2; ++nj) {
      bf0[nj] = *reinterpret_cast<const short8*>((const char*)Bs + (wc + nj * 16) * 128 + fb0);
      bf1[nj] = *reinterpret_cast<const short8*>((const char*)Bs + (wc + nj * 16) * 128 + fb1);
    }
    #pragma unroll
    for (int mi = 0; mi < 2; ++mi)
      #pragma unroll
      for (int nj = 0; nj < 2; ++nj) {
        acc[mi][nj] = __builtin_amdgcn_mfma_f32_16x16x32_bf16(af0[mi], bf0[nj], acc[mi][nj], 0, 0, 0);
        acc[mi][nj] = __builtin_amdgcn_mfma_f32_16x16x32_bf16(af1[mi], bf1[nj], acc[mi][nj], 0, 0, 0);
      }
  }
  #pragma unroll
  for (int mi = 0; mi < 2; ++mi) {
    #pragma unroll
    for (int nj = 0; nj < 2; ++nj) {
      const int col = col0 + wc + nj * 16 + lr;
      const float bv = bias ? bias[col] : 0.0f;
      #pragma unroll
      for (int rg = 0; rg < 4; ++rg) {
        const int row = row0 + wr + mi * 16 + lg * 4 + rg;
        float v = acc[mi][nj][rg] + bv;
        if constexpr (EPI == 1) v = 0.5f * v * (1.0f + erff(v * 0.70710678118654752f));
        if constexpr (EPI == 2) {
          reinterpret_cast<float*>(Cv)[(size_t)row * N + col] = v + resid[(size_t)row * N + col];
        } else {
          reinterpret_cast<bf16*>(Cv)[(size_t)row * N + col] = __float2bfloat16(v);
        }
      }
    }
  }
}

// ---------------- reshape QKV (fp16 in): q [BH,N,64] (scaled); K,V -> 32x32 A-frag-major fp16 ----------------
// KF[bh][t32][dc(4)][lane l][j]: = K[kv = t32*32 + (l&31)][d = dc*16 + (l>>5)*8 + j]
// VF[bh][t32][db(2)][c(2)][lane l][j]: = V[n = t32*32 + c*16 + 4*(l>>5) + (j&3) + 8*(j>>2)][d = db*32 + (l&31)]
__global__ __launch_bounds__(256) void reshape_qkv(const __half* __restrict__ C,
                                                   __half* __restrict__ q,
                                                   __half* __restrict__ KF,
                                                   __half* __restrict__ VF) {
  const int nt = blockIdx.x;   // 64-row tile
  const int bh = blockIdx.y;
  const int b = bh >> 3, h = bh & 7;
  __shared__ alignas(16) __half vs[64][72];  // [d][n] transposed tile
  const int tid = threadIdx.x;
  const float qs = 0.125f * 1.44269504088896340736f;
  #pragma unroll
  for (int i = 0; i < 16; ++i) {
    const int idx = i * 256 + tid;
    const int rr = idx >> 6, c = idx & 63;
    const size_t crow = ((size_t)b * 4096 + nt * 64 + rr) * 1536;
    const size_t onb = ((size_t)bh * 4096 + nt * 64 + rr) * 64 + c;
    q[onb] = __float2half(__half2float(C[crow + h * 64 + c]) * qs);
    vs[c][rr] = C[crow + 1024 + h * 64 + c];   // transposed: vs[d][n]
  }
  // K frag-major (contiguous 16B source chunks, no LDS needed)
  #pragma unroll
  for (int i = 0; i < 2; ++i) {
    const int s = i * 256 + tid;               // 0..511
    const int half_ = s >> 8, dc = (s >> 6) & 3, l = s & 63;
    const int l31 = l & 31, hi2 = l >> 5;
    const __half* src = C + ((size_t)b * 4096 + nt * 64 + half_ * 32 + l31) * 1536
                          + 512 + h * 64 + dc * 16 + hi2 * 8;
    __half* dst = KF + ((size_t)bh * 128 + nt * 2 + half_) * 2048 + dc * 512 + (size_t)l * 8;
    *reinterpret_cast<short8*>(dst) = *reinterpret_cast<const short8*>(src);
  }
  __syncthreads();
  #pragma unroll
  for (int i = 0; i < 2; ++i) {
    const int s = i * 256 + tid;               // 0..511
    const int half_ = (s >> 8) & 1, db = (s >> 7) & 1, c = (s >> 6) & 1, l = s & 63;
    const int d = db * 32 + (l & 31);
    const int n0 = half_ * 32 + c * 16 + ((l >> 5) << 2);
    const short4 lo = *reinterpret_cast<const short4*>(&vs[d][n0]);
    const short4 hi = *reinterpret_cast<const short4*>(&vs[d][n0 + 8]);
    short8 v;
    v[0] = lo.x; v[1] = lo.y; v[2] = lo.z; v[3] = lo.w;
    v[4] = hi.x; v[5] = hi.y; v[6] = hi.z; v[7] = hi.w;
    __half* dst = VF + ((size_t)bh * 128 + nt * 2 + half_) * 2048 + (db * 2 + c) * 512 + (size_t)l * 8;
    *reinterpret_cast<short8*>(dst) = v;
  }
}

// ---------------- flash attention: fp16 32x32 MFMA, 64 q/wave (2 B-operand sets), barrier-free loop ----------------
// Block = 4 waves: qg = w>>1 (which 64-q slab), kvh = w&1 (kv half). Split-KV merge per q-set at end.
// XCD swizzle: XCD k handles heads {2k,2k+1}; per-XCD KV working set 2MB (L2-resident).
__global__ __launch_bounds__(256, 2) void attn_kernel(const __half* __restrict__ Q,
                                                      const __half* __restrict__ KF,
                                                      const __half* __restrict__ VF,
                                                      bf16* __restrict__ Out) {
  // bijective swizzle over 512 blocks: bid -> swz = (bid%8)*64 + bid/8
  const int bid = blockIdx.y * 32 + blockIdx.x;
  const int swz = (bid & 7) * 64 + (bid >> 3);
  const int qt = swz & 31;     // 0..31 (128 q rows per block)
  const int bh = swz >> 5;     // 0..15
  const int b = bh >> 3, h = bh & 7;
  __shared__ alignas(16) char smem[17408];   // merge only (one q-set at a time)
  const int tid = threadIdx.x, w = tid >> 6, lane = tid & 63;
  const int qg = w >> 1, kvh = w & 1;
  const int l31 = lane & 31, hi = lane >> 5;

  // ---- Q frags for both q-sets (B operand: col=q=l31, k-slots hi*8+j) ----
  const __half* qbase = Q + ((size_t)bh * 4096 + qt * 128 + qg * 64 + l31) * 64 + hi * 8;
  half8 qf0[4], qf1[4];
  #pragma unroll
  for (int dc = 0; dc < 4; ++dc) {
    qf0[dc] = *reinterpret_cast<const half8*>(qbase + dc * 16);
    qf1[dc] = *reinterpret_cast<const half8*>(qbase + 2048 + dc * 16);  // +32 rows
  }

  const char* kfp = (const char*)KF + (size_t)bh * 524288 + (size_t)kvh * 262144 + lane * 16;
  const char* vfp = (const char*)VF + (size_t)bh * 524288 + (size_t)kvh * 262144 + lane * 16;

  f32x16 O00 = {}, O01 = {};   // q-set 0: d 0..31 / d 32..63
  f32x16 O10 = {}, O11 = {};   // q-set 1
  float m0 = -1e30f, l0 = 0.0f, m1 = -1e30f, l1 = 0.0f;

  for (int t = 0; t < 64; ++t) {
    const half8 va00 = *reinterpret_cast<const half8*>(vfp);
    const half8 va01 = *reinterpret_cast<const half8*>(vfp + 1024);
    const half8 va10 = *reinterpret_cast<const half8*>(vfp + 2048);
    const half8 va11 = *reinterpret_cast<const half8*>(vfp + 3072);
    vfp += 4096;
    const half8 kf0 = *reinterpret_cast<const half8*>(kfp);
    const half8 kf1 = *reinterpret_cast<const half8*>(kfp + 1024);
    const half8 kf2 = *reinterpret_cast<const half8*>(kfp + 2048);
    const half8 kf3 = *reinterpret_cast<const half8*>(kfp + 3072);
    kfp += 4096;
    // ---- S^T[kv][q] for both q-sets ----
    f32x16 S0 = {}, S1 = {};
    __builtin_amdgcn_s_setprio(1);
    S0 = __builtin_amdgcn_mfma_f32_32x32x16_f16(kf0, qf0[0], S0, 0, 0, 0);
    S1 = __builtin_amdgcn_mfma_f32_32x32x16_f16(kf0, qf1[0], S1, 0, 0, 0);
    S0 = __builtin_amdgcn_mfma_f32_32x32x16_f16(kf1, qf0[1], S0, 0, 0, 0);
    S1 = __builtin_amdgcn_mfma_f32_32x32x16_f16(kf1, qf1[1], S1, 0, 0, 0);
    S0 = __builtin_amdgcn_mfma_f32_32x32x16_f16(kf2, qf0[2], S0, 0, 0, 0);
    S1 = __builtin_amdgcn_mfma_f32_32x32x16_f16(kf2, qf1[2], S1, 0, 0, 0);
    S0 = __builtin_amdgcn_mfma_f32_32x32x16_f16(kf3, qf0[3], S0, 0, 0, 0);
    S1 = __builtin_amdgcn_mfma_f32_32x32x16_f16(kf3, qf1[3], S1, 0, 0, 0);
    __builtin_amdgcn_s_setprio(0);
    union U8 { unsigned u[4]; half8 h8; } p00, p01, p10, p11;
    // ---- softmax + pack, q-set 0 ----
    {
      float a0 = fmaxf(fmaxf(S0[0], S0[1]), fmaxf(S0[2], S0[3]));
      float a1 = fmaxf(fmaxf(S0[4], S0[5]), fmaxf(S0[6], S0[7]));
      float a2 = fmaxf(fmaxf(S0[8], S0[9]), fmaxf(S0[10], S0[11]));
      float a3 = fmaxf(fmaxf(S0[12], S0[13]), fmaxf(S0[14], S0[15]));
      float rmax = fmaxf(fmaxf(a0, a1), fmaxf(a2, a3));
      rmax = fmaxf(rmax, __shfl_xor(rmax, 32));
      if (!__all(rmax <= m0 + 8.0f)) {
        const float mnew = fmaxf(m0, rmax);
        const float fsc = __builtin_amdgcn_exp2f(m0 - mnew);
        l0 *= fsc;
        #pragma unroll
        for (int i = 0; i < 16; ++i) { O00[i] *= fsc; O01[i] *= fsc; }
        m0 = mnew;
      }
      #pragma unroll
      for (int i = 0; i < 16; ++i) S0[i] = __builtin_amdgcn_exp2f(S0[i] - m0);
      float s0 = (S0[0] + S0[1]) + (S0[2] + S0[3]);
      float s1 = (S0[4] + S0[5]) + (S0[6] + S0[7]);
      float s2 = (S0[8] + S0[9]) + (S0[10] + S0[11]);
      float s3 = (S0[12] + S0[13]) + (S0[14] + S0[15]);
      float rsum = (s0 + s1) + (s2 + s3);
      rsum += __shfl_xor(rsum, 32);
      l0 += rsum;
      p00.u[0] = pack_f16x2(S0[0], S0[1]);   p00.u[1] = pack_f16x2(S0[2], S0[3]);
      p00.u[2] = pack_f16x2(S0[4], S0[5]);   p00.u[3] = pack_f16x2(S0[6], S0[7]);
      p01.u[0] = pack_f16x2(S0[8], S0[9]);   p01.u[1] = pack_f16x2(S0[10], S0[11]);
      p01.u[2] = pack_f16x2(S0[12], S0[13]); p01.u[3] = pack_f16x2(S0[14], S0[15]);
    }
    // ---- softmax + pack, q-set 1 ----
    {
      float a0 = fmaxf(fmaxf(S1[0], S1[1]), fmaxf(S1[2], S1[3]));
      float a1 = fmaxf(fmaxf(S1[4], S1[5]), fmaxf(S1[6], S1[7]));
      float a2 = fmaxf(fmaxf(S1[8], S1[9]), fmaxf(S1[10], S1[11]));
      float a3 = fmaxf(fmaxf(S1[12], S1[13]), fmaxf(S1[14], S1[15]));
      float rmax = fmaxf(fmaxf(a0, a1), fmaxf(a2, a3));
      rmax = fmaxf(rmax, __shfl_xor(rmax, 32));
      if (!__all(rmax <= m1 + 8.0f)) {
        const float mnew = fmaxf(m1, rmax);
        const float fsc = __builtin_amdgcn_exp2f(m1 - mnew);
        l1 *= fsc;
        #pragma unroll
        for (int i = 0; i < 16; ++i) { O10[i] *= fsc; O11[i] *= fsc; }
        m1 = mnew;
      }
      #pragma unroll
      for (int i = 0; i < 16; ++i) S1[i] = __builtin_amdgcn_exp2f(S1[i] - m1);
      float s0 = (S1[0] + S1[1]) + (S1[2] + S1[3]);
      float s1 = (S1[4] + S1[5]) + (S1[6] + S1[7]);
      float s2 = (S1[8] + S1[9]) + (S1[10] + S1[11]);
      float s3 = (S1[12] + S1[13]) + (S1[14] + S1[15]);
      float rsum = (s0 + s1) + (s2 + s3);
      rsum += __shfl_xor(rsum, 32);
      l1 += rsum;
      p10.u[0] = pack_f16x2(S1[0], S1[1]);   p10.u[1] = pack_f16x2(S1[2], S1[3]);
      p10.u[2] = pack_f16x2(S1[4], S1[5]);   p10.u[3] = pack_f16x2(S1[6], S1[7]);
      p11.u[0] = pack_f16x2(S1[8], S1[9]);   p11.u[1] = pack_f16x2(S1[10], S1[11]);
      p11.u[2] = pack_f16x2(S1[12], S1[13]); p11.u[3] = pack_f16x2(S1[14], S1[15]);
    }
    // ---- O^T[d][q] += V^T . P^T (both q-sets share the V frags) ----
    __builtin_amdgcn_s_setprio(1);
    O00 = __builtin_amdgcn_mfma_f32_32x32x16_f16(va00, p00.h8, O00, 0, 0, 0);
    O10 = __builtin_amdgcn_mfma_f32_32x32x16_f16(va00, p10.h8, O10, 0, 0, 0);
    O00 = __builtin_amdgcn_mfma_f32_32x32x16_f16(va01, p01.h8, O00, 0, 0, 0);
    O10 = __builtin_amdgcn_mfma_f32_32x32x16_f16(va01, p11.h8, O10, 0, 0, 0);
    O01 = __builtin_amdgcn_mfma_f32_32x32x16_f16(va10, p00.h8, O01, 0, 0, 0);
    O11 = __builtin_amdgcn_mfma_f32_32x32x16_f16(va10, p10.h8, O11, 0, 0, 0);
    O01 = __builtin_amdgcn_mfma_f32_32x32x16_f16(va11, p01.h8, O01, 0, 0, 0);
    O11 = __builtin_amdgcn_mfma_f32_32x32x16_f16(va11, p11.h8, O11, 0, 0, 0);
    __builtin_amdgcn_s_setprio(0);
  }

  // ---- split-KV merge, one q-set at a time (reuses the same LDS area) ----
  float* area = reinterpret_cast<float*>(smem) + qg * 2176;  // 2048 O + 64 m + 64 l floats
  #pragma unroll
  for (int qs = 0; qs < 2; ++qs) {
    const f32x16& Pd0 = qs ? O10 : O00;
    const f32x16& Pd1 = qs ? O11 : O01;
    const float mw = qs ? m1 : m0;
    const float lw = qs ? l1 : l0;
    __syncthreads();
    if (kvh) {
      #pragma unroll
      for (int r = 0; r < 16; ++r) {
        area[r * 64 + lane] = Pd0[r];
        area[(16 + r) * 64 + lane] = Pd1[r];
      }
      area[2048 + lane] = mw;
      area[2112 + lane] = lw;
    }
    __syncthreads();
    if (!kvh) {
      const float mB = area[2048 + lane], lB = area[2112 + lane];
      const float mx = fmaxf(mw, mB);
      const float fa = __builtin_amdgcn_exp2f(mw - mx);
      const float fb = __builtin_amdgcn_exp2f(mB - mx);
      const float inv = 1.0f / (lw * fa + lB * fb);
      const int qrow2 = qt * 128 + qg * 64 + qs * 32 + l31;
      bf16* ob = Out + ((size_t)b * 4096 + qrow2) * 512 + h * 64 + hi * 4;
      #pragma unroll
      for (int db = 0; db < 2; ++db) {
        #pragma unroll
        for (int rq = 0; rq < 4; ++rq) {
          const int r = rq * 4;
          float v0 = ((db ? Pd1[r + 0] : Pd0[r + 0]) * fa + area[(db * 16 + r + 0) * 64 + lane] * fb) * inv;
          float v1 = ((db ? Pd1[r + 1] : Pd0[r + 1]) * fa + area[(db * 16 + r + 1) * 64 + lane] * fb) * inv;
          float v2 = ((db ? Pd1[r + 2] : Pd0[r + 2]) * fa + area[(db * 16 + r + 2) * 64 + lane] * fb) * inv;
          float v3 = ((db ? Pd1[r + 3] : Pd0[r + 3]) * fa + area[(db * 16 + r + 3) * 64 + lane] * fb) * inv;
          uint2 st;
          st.x = pack_bf16x2(v0, v1);
          st.y = pack_bf16x2(v2, v3);
          *reinterpret_cast<uint2*>(ob + db * 32 + rq * 8) = st;
        }
      }
    }
  }
}

// ---------------- host ----------------
extern "C" void kernel_launch(void* const* d_in, const int* in_sizes, int n_in,
                              void* d_out, int out_size, void* d_ws, size_t ws_size,
                              hipStream_t stream) {
  const float* x      = (const float*)d_in[0];
  const float* ln1_g  = (const float*)d_in[1];
  const float* ln1_b  = (const float*)d_in[2];
  const float* ln2_g  = (const float*)d_in[3];
  const float* ln2_b  = (const float*)d_in[4];
  const float* qkv_w  = (const float*)d_in[5];
  const float* qkv_b  = (const float*)d_in[6];
  const float* proj_w = (const float*)d_in[7];
  const float* proj_b = (const float*)d_in[8];
  const float* fc1_w  = (const float*)d_in[9];
  const float* fc1_b  = (const float*)d_in[10];
  const float* fc2_w  = (const float*)d_in[11];
  const float* fc2_b  = (const float*)d_in[12];

  char* ws = (char*)d_ws;
  constexpr size_t o_qkvw = 0;
  constexpr size_t o_projw = 1572864;
  constexpr size_t o_fc1w  = 2097152;
  constexpr size_t o_fc2w  = 4194304;
  constexpr size_t o_h     = 6291456;
  constexpr size_t o_qkvC  = 14680064;
  constexpr size_t o_q     = 39845888;
  constexpr size_t o_k     = 48234496;
  constexpr size_t o_vt    = 56623104;
  constexpr size_t o_attn  = 65011712;
  constexpr size_t o_x2    = 73400320;
  constexpr size_t o_fc1o  = o_qkvC;
  constexpr size_t needed  = 90177536;
  if (ws_size < needed) return;

  bf16* qkvw_bf = (bf16*)(ws + o_qkvw);
  bf16* projw_bf = (bf16*)(ws + o_projw);
  bf16* fc1w_bf = (bf16*)(ws + o_fc1w);
  bf16* fc2w_bf = (bf16*)(ws + o_fc2w);
  bf16* h     = (bf16*)(ws + o_h);
  __half* qkvC = (__half*)(ws + o_qkvC);
  __half* q    = (__half*)(ws + o_q);
  __half* kf   = (__half*)(ws + o_k);
  __half* vf   = (__half*)(ws + o_vt);
  bf16* attn  = (bf16*)(ws + o_attn);
  float* x2   = (float*)(ws + o_x2);
  bf16* fc1o  = (bf16*)(ws + o_fc1o);
  float* out  = (float*)d_out;

  cvt_all<<<3072, 256, 0, stream>>>(qkv_w, qkvw_bf, proj_w, projw_bf, fc1_w, fc1w_bf, fc2_w, fc2w_bf);

  ln_kernel<<<2048, 256, 0, stream>>>(x, ln1_g, ln1_b, h);
  gemm_bt<3><<<dim3(64, 12), 256, 0, stream>>>(h, qkvw_bf, qkv_b, nullptr, qkvC, 8192, 1536, 512);
  reshape_qkv<<<dim3(64, 16), 256, 0, stream>>>(qkvC, q, kf, vf);
  attn_kernel<<<dim3(32, 16), 256, 0, stream>>>(q, kf, vf, attn);
  gemm_bt64<2><<<dim3(128, 8), 256, 0, stream>>>(attn, projw_bf, proj_b, x, x2, 8192, 512, 512);
  ln_kernel<<<2048, 256, 0, stream>>>(x2, ln2_g, ln2_b, h);
  gemm_bt<1><<<dim3(64, 16), 256, 0, stream>>>(h, fc1w_bf, fc1_b, nullptr, fc1o, 8192, 2048, 512);
  gemm_bt64<2><<<dim3(128, 8), 256, 0, stream>>>(fc1o, fc2w_bf, fc2_b, x2, out, 8192, 512, 2048);
}

// Round 18
// 235.035 us; speedup vs baseline: 1.6733x; 1.0105x over previous
//
#include <hip/hip_runtime.h>
#include <hip/hip_bf16.h>
#include <hip/hip_fp16.h>
#include <string.h>

using bf16 = __hip_bfloat16;
typedef __attribute__((ext_vector_type(8))) short short8;       // 8 x bf16 MFMA A/B frag
typedef __attribute__((ext_vector_type(8))) _Float16 half8;     // 8 x fp16 MFMA A/B frag
typedef __attribute__((ext_vector_type(4))) float f32x4;        // 16x16 MFMA C/D frag
typedef __attribute__((ext_vector_type(16))) float f32x16;      // 32x32 MFMA C/D frag

#define GAS __attribute__((address_space(1)))
#define LAS __attribute__((address_space(3)))

__device__ __forceinline__ void gld_lds16(const void* g, void* l) {
  __builtin_amdgcn_global_load_lds((const GAS void*)g, (LAS void*)l, 16, 0, 0);
}

__device__ __forceinline__ unsigned short f2bfu(float f) {
  bf16 h = __float2bfloat16(f);
  return *reinterpret_cast<unsigned short*>(&h);
}

__device__ __forceinline__ unsigned pack_bf16x2(float lo, float hi) {
  __hip_bfloat162 v = __float22bfloat162_rn(make_float2(lo, hi));
  unsigned u;
  __builtin_memcpy(&u, &v, 4);
  return u;
}

__device__ __forceinline__ unsigned pack_f16x2(float lo, float hi) {
  __half2 v = __float22half2_rn(make_float2(lo, hi));
  unsigned u;
  __builtin_memcpy(&u, &v, 4);
  return u;
}

// XCD-aware bijective remap: XCD k owns row-chunk k (all col-tiles). Requires grid % 8 == 0.
__device__ __forceinline__ void xcd_tile_remap(int& bx, int& by) {
  const int bidl = blockIdx.y * gridDim.x + blockIdx.x;
  const int xcd = bidl & 7;
  const int j = bidl >> 3;
  const int R = gridDim.x >> 3;   // row-tiles per XCD chunk
  bx = xcd * R + (j % R);
  by = j / R;
}

// ---------------- all weights f32 -> bf16 in one launch ----------------
__global__ __launch_bounds__(256) void cvt_all(const float* __restrict__ w0, bf16* __restrict__ o0,
                                               const float* __restrict__ w1, bf16* __restrict__ o1,
                                               const float* __restrict__ w2, bf16* __restrict__ o2,
                                               const float* __restrict__ w3, bf16* __restrict__ o3) {
  int i = blockIdx.x * 256 + threadIdx.x;   // f4 index, total 786432
  const float* src; bf16* dst; int off;
  if (i < 196608)      { src = w0; dst = o0; off = i; }
  else if (i < 262144) { src = w1; dst = o1; off = i - 196608; }
  else if (i < 524288) { src = w2; dst = o2; off = i - 262144; }
  else                 { src = w3; dst = o3; off = i - 524288; }
  float4 v = reinterpret_cast<const float4*>(src)[off];
  ushort4 o;
  o.x = f2bfu(v.x); o.y = f2bfu(v.y); o.z = f2bfu(v.z); o.w = f2bfu(v.w);
  reinterpret_cast<ushort4*>(dst)[off] = o;
}

// ---------------- LayerNorm (fp32 in, bf16 out), one wave per 512-row ----------------
__global__ __launch_bounds__(256) void ln_kernel(const float* __restrict__ x,
                                                 const float* __restrict__ g,
                                                 const float* __restrict__ b,
                                                 bf16* __restrict__ out) {
  const int row = blockIdx.x * 4 + (threadIdx.x >> 6);
  const int lane = threadIdx.x & 63;
  const float4* xr = reinterpret_cast<const float4*>(x + (size_t)row * 512);
  float4 v0 = xr[lane], v1 = xr[64 + lane];
  float s  = v0.x + v0.y + v0.z + v0.w + v1.x + v1.y + v1.z + v1.w;
  float s2 = v0.x*v0.x + v0.y*v0.y + v0.z*v0.z + v0.w*v0.w
           + v1.x*v1.x + v1.y*v1.y + v1.z*v1.z + v1.w*v1.w;
  #pragma unroll
  for (int d = 1; d < 64; d <<= 1) { s += __shfl_xor(s, d); s2 += __shfl_xor(s2, d); }
  const float mu = s * (1.0f / 512.0f);
  const float var = s2 * (1.0f / 512.0f) - mu * mu;
  const float rstd = rsqrtf(var + 1e-5f);
  const float4* g4 = reinterpret_cast<const float4*>(g);
  const float4* b4 = reinterpret_cast<const float4*>(b);
  float4 ga = g4[lane], gb = g4[64 + lane], ba = b4[lane], bb = b4[64 + lane];
  ushort4 o0, o1;
  o0.x = f2bfu((v0.x - mu) * rstd * ga.x + ba.x);
  o0.y = f2bfu((v0.y - mu) * rstd * ga.y + ba.y);
  o0.z = f2bfu((v0.z - mu) * rstd * ga.z + ba.z);
  o0.w = f2bfu((v0.w - mu) * rstd * ga.w + ba.w);
  o1.x = f2bfu((v1.x - mu) * rstd * gb.x + bb.x);
  o1.y = f2bfu((v1.y - mu) * rstd * gb.y + bb.y);
  o1.z = f2bfu((v1.z - mu) * rstd * gb.z + bb.z);
  o1.w = f2bfu((v1.w - mu) * rstd * gb.w + bb.w);
  ushort4* orow = reinterpret_cast<ushort4*>(out + (size_t)row * 512);
  orow[lane] = o0;
  orow[64 + lane] = o1;
}

// ---------------- GEMM 128x128: C[M,N] = A[M,K] * B[N,K]^T (+bias, epilogue), XCD-swizzled ----------------
// EPI 0: bf16 out. 1: GELU->bf16. 2: +resid(f32)->f32. 3: fp16 out.
template <int EPI>
__global__ __launch_bounds__(256) void gemm_bt(const bf16* __restrict__ A,
                                               const bf16* __restrict__ B,
                                               const float* __restrict__ bias,
                                               const float* __restrict__ resid,
                                               void* __restrict__ Cv,
                                               int M, int N, int K) {
  __shared__ bf16 As[128 * 32];
  __shared__ bf16 Bs[128 * 32];
  const int tid = threadIdx.x;
  const int lane = tid & 63, wid = tid >> 6;
  const int lr = lane & 15, lg = lane >> 4;
  int bx, by;
  xcd_tile_remap(bx, by);
  const int row0 = bx * 128, col0 = by * 128;
  const int wr = (wid >> 1) * 64, wc = (wid & 1) * 64;
  f32x4 acc[4][4] = {};
  const int r1 = tid >> 2,          c1 = (tid & 3) * 8;
  const int r2 = (256 + tid) >> 2,  c2 = ((256 + tid) & 3) * 8;
  for (int kt = 0; kt < K; kt += 32) {
    __syncthreads();
    gld_lds16(A + (size_t)(row0 + r1) * K + kt + c1, As + tid * 8);
    gld_lds16(A + (size_t)(row0 + r2) * K + kt + c2, As + (256 + tid) * 8);
    gld_lds16(B + (size_t)(col0 + r1) * K + kt + c1, Bs + tid * 8);
    gld_lds16(B + (size_t)(col0 + r2) * K + kt + c2, Bs + (256 + tid) * 8);
    __syncthreads();
    short8 af[4], bfr[4];
    #pragma unroll
    for (int mi = 0; mi < 4; ++mi)
      af[mi] = *reinterpret_cast<const short8*>(&As[(wr + mi * 16 + lr) * 32 + lg * 8]);
    #pragma unroll
    for (int nj = 0; nj < 4; ++nj)
      bfr[nj] = *reinterpret_cast<const short8*>(&Bs[(wc + nj * 16 + lr) * 32 + lg * 8]);
    #pragma unroll
    for (int mi = 0; mi < 4; ++mi)
      #pragma unroll
      for (int nj = 0; nj < 4; ++nj)
        acc[mi][nj] = __builtin_amdgcn_mfma_f32_16x16x32_bf16(af[mi], bfr[nj], acc[mi][nj], 0, 0, 0);
  }
  #pragma unroll
  for (int mi = 0; mi < 4; ++mi) {
    #pragma unroll
    for (int nj = 0; nj < 4; ++nj) {
      const int col = col0 + wc + nj * 16 + lr;
      const float bv = bias ? bias[col] : 0.0f;
      #pragma unroll
      for (int rg = 0; rg < 4; ++rg) {
        const int row = row0 + wr + mi * 16 + lg * 4 + rg;
        float v = acc[mi][nj][rg] + bv;
        if constexpr (EPI == 1) v = 0.5f * v * (1.0f + erff(v * 0.70710678118654752f));
        if constexpr (EPI == 2) {
          reinterpret_cast<float*>(Cv)[(size_t)row * N + col] = v + resid[(size_t)row * N + col];
        } else if constexpr (EPI == 3) {
          reinterpret_cast<__half*>(Cv)[(size_t)row * N + col] = __float2half(v);
        } else {
          reinterpret_cast<bf16*>(Cv)[(size_t)row * N + col] = __float2bfloat16(v);
        }
      }
    }
  }
}

// ---------------- GEMM 64x64 (BK=64, swizzled LDS), XCD-swizzled: for N=512 GEMMs ----------------
template <int EPI>
__global__ __launch_bounds__(256) void gemm_bt64(const bf16* __restrict__ A,
                                                 const bf16* __restrict__ B,
                                                 const float* __restrict__ bias,
                                                 const float* __restrict__ resid,
                                                 void* __restrict__ Cv,
                                                 int M, int N, int K) {
  __shared__ bf16 As[64 * 64];   // [64 rows][128B], XOR-swizzled
  __shared__ bf16 Bs[64 * 64];
  const int tid = threadIdx.x;
  const int lane = tid & 63, wid = tid >> 6;
  const int lr = lane & 15, lg = lane >> 4;
  int bx, by;
  xcd_tile_remap(bx, by);
  const int row0 = bx * 64, col0 = by * 64;
  const int wr = (wid >> 1) * 32, wc = (wid & 1) * 32;
  f32x4 acc[2][2] = {};
  const int xsw = (lr & 7) << 4;
  const int fb0 = lr * 128 + ((lg * 16) ^ xsw);
  const int fb1 = lr * 128 + ((64 + lg * 16) ^ xsw);
  const int ph0 = tid * 16, ph1 = (256 + tid) * 16;
  const int r0 = ph0 >> 7, r1 = ph1 >> 7;
  const int lb0 = ph0 ^ ((r0 & 7) << 4), lb1 = ph1 ^ ((r1 & 7) << 4);
  const char* Ab0 = (const char*)A + (size_t)(row0 + r0) * K * 2 + (lb0 & 127);
  const char* Ab1 = (const char*)A + (size_t)(row0 + r1) * K * 2 + (lb1 & 127);
  const char* Bb0 = (const char*)B + (size_t)(col0 + r0) * K * 2 + (lb0 & 127);
  const char* Bb1 = (const char*)B + (size_t)(col0 + r1) * K * 2 + (lb1 & 127);
  for (int kt = 0; kt < K; kt += 64) {
    __syncthreads();
    gld_lds16(Ab0 + kt * 2, (char*)As + ph0);
    gld_lds16(Ab1 + kt * 2, (char*)As + ph1);
    gld_lds16(Bb0 + kt * 2, (char*)Bs + ph0);
    gld_lds16(Bb1 + kt * 2, (char*)Bs + ph1);
    __syncthreads();
    short8 af0[2], af1[2], bf0[2], bf1[2];
    #pragma unroll
    for (int mi = 0; mi < 2; ++mi) {
      af0[mi] = *reinterpret_cast<const short8*>((const char*)As + (wr + mi * 16) * 128 + fb0);
      af1[mi] = *reinterpret_cast<const short8*>((const char*)As + (wr + mi * 16) * 128 + fb1);
    }
    #pragma unroll
    for (int nj = 0; nj < 2; ++nj) {
      bf0[nj] = *reinterpret_cast<const short8*>((const char*)Bs + (wc + nj * 16) * 128 + fb0);
      bf1[nj] = *reinterpret_cast<const short8*>((const char*)Bs + (wc + nj * 16) * 128 + fb1);
    }
    #pragma unroll
    for (int mi = 0; mi < 2; ++mi)
      #pragma unroll
      for (int nj = 0; nj < 2; ++nj) {
        acc[mi][nj] = __builtin_amdgcn_mfma_f32_16x16x32_bf16(af0[mi], bf0[nj], acc[mi][nj], 0, 0, 0);
        acc[mi][nj] = __builtin_amdgcn_mfma_f32_16x16x32_bf16(af1[mi], bf1[nj], acc[mi][nj], 0, 0, 0);
      }
  }
  #pragma unroll
  for (int mi = 0; mi < 2; ++mi) {
    #pragma unroll
    for (int nj = 0; nj < 2; ++nj) {
      const int col = col0 + wc + nj * 16 + lr;
      const float bv = bias ? bias[col] : 0.0f;
      #pragma unroll
      for (int rg = 0; rg < 4; ++rg) {
        const int row = row0 + wr + mi * 16 + lg * 4 + rg;
        float v = acc[mi][nj][rg] + bv;
        if constexpr (EPI == 1) v = 0.5f * v * (1.0f + erff(v * 0.70710678118654752f));
        if constexpr (EPI == 2) {
          reinterpret_cast<float*>(Cv)[(size_t)row * N + col] = v + resid[(size_t)row * N + col];
        } else {
          reinterpret_cast<bf16*>(Cv)[(size_t)row * N + col] = __float2bfloat16(v);
        }
      }
    }
  }
}

// ---------------- reshape QKV (fp16 in): q [BH,N,64] (scaled); K,V -> 32x32 A-frag-major fp16 ----------------
// KF[bh][t32][dc(4)][lane l][j]: = K[kv = t32*32 + (l&31)][d = dc*16 + (l>>5)*8 + j]
// VF[bh][t32][db(2)][c(2)][lane l][j]: = V[n = t32*32 + c*16 + 4*(l>>5) + (j&3) + 8*(j>>2)][d = db*32 + (l&31)]
__global__ __launch_bounds__(256) void reshape_qkv(const __half* __restrict__ C,
                                                   __half* __restrict__ q,
                                                   __half* __restrict__ KF,
                                                   __half* __restrict__ VF) {
  const int nt = blockIdx.x;   // 64-row tile
  const int bh = blockIdx.y;
  const int b = bh >> 3, h = bh & 7;
  __shared__ alignas(16) __half vs[64][72];  // [d][n] transposed tile
  const int tid = threadIdx.x;
  const float qs = 0.125f * 1.44269504088896340736f;
  #pragma unroll
  for (int i = 0; i < 16; ++i) {
    const int idx = i * 256 + tid;
    const int rr = idx >> 6, c = idx & 63;
    const size_t crow = ((size_t)b * 4096 + nt * 64 + rr) * 1536;
    const size_t onb = ((size_t)bh * 4096 + nt * 64 + rr) * 64 + c;
    q[onb] = __float2half(__half2float(C[crow + h * 64 + c]) * qs);
    vs[c][rr] = C[crow + 1024 + h * 64 + c];   // transposed: vs[d][n]
  }
  // K frag-major (contiguous 16B source chunks, no LDS needed)
  #pragma unroll
  for (int i = 0; i < 2; ++i) {
    const int s = i * 256 + tid;               // 0..511
    const int half_ = s >> 8, dc = (s >> 6) & 3, l = s & 63;
    const int l31 = l & 31, hi2 = l >> 5;
    const __half* src = C + ((size_t)b * 4096 + nt * 64 + half_ * 32 + l31) * 1536
                          + 512 + h * 64 + dc * 16 + hi2 * 8;
    __half* dst = KF + ((size_t)bh * 128 + nt * 2 + half_) * 2048 + dc * 512 + (size_t)l * 8;
    *reinterpret_cast<short8*>(dst) = *reinterpret_cast<const short8*>(src);
  }
  __syncthreads();
  #pragma unroll
  for (int i = 0; i < 2; ++i) {
    const int s = i * 256 + tid;               // 0..511
    const int half_ = (s >> 8) & 1, db = (s >> 7) & 1, c = (s >> 6) & 1, l = s & 63;
    const int d = db * 32 + (l & 31);
    const int n0 = half_ * 32 + c * 16 + ((l >> 5) << 2);
    const short4 lo = *reinterpret_cast<const short4*>(&vs[d][n0]);
    const short4 hi = *reinterpret_cast<const short4*>(&vs[d][n0 + 8]);
    short8 v;
    v[0] = lo.x; v[1] = lo.y; v[2] = lo.z; v[3] = lo.w;
    v[4] = hi.x; v[5] = hi.y; v[6] = hi.z; v[7] = hi.w;
    __half* dst = VF + ((size_t)bh * 128 + nt * 2 + half_) * 2048 + (db * 2 + c) * 512 + (size_t)l * 8;
    *reinterpret_cast<short8*>(dst) = v;
  }
}

// ---------------- flash attention: fp16 32x32 MFMA, 64 q/wave, register ping-pong KV prefetch ----------------
// Block = 4 waves: qg = w>>1 (64-q slab), kvh = w&1 (kv half). Split-KV merge per q-set at end.
struct Frags { half8 k0, k1, k2, k3, v0, v1, v2, v3; };

__global__ __launch_bounds__(256, 2) void attn_kernel(const __half* __restrict__ Q,
                                                      const __half* __restrict__ KF,
                                                      const __half* __restrict__ VF,
                                                      bf16* __restrict__ Out) {
  // bijective XCD swizzle over 512 blocks: XCD k handles heads {2k,2k+1} (KV L2-resident)
  const int bid = blockIdx.y * 32 + blockIdx.x;
  const int swz = (bid & 7) * 64 + (bid >> 3);
  const int qt = swz & 31;     // 0..31 (128 q rows per block)
  const int bh = swz >> 5;     // 0..15
  const int b = bh >> 3, h = bh & 7;
  __shared__ alignas(16) char smem[17408];   // merge only (one q-set at a time)
  const int tid = threadIdx.x, w = tid >> 6, lane = tid & 63;
  const int qg = w >> 1, kvh = w & 1;
  const int l31 = lane & 31, hi = lane >> 5;

  // ---- Q frags for both q-sets (B operand: col=q=l31, k-slots hi*8+j) ----
  const __half* qbase = Q + ((size_t)bh * 4096 + qt * 128 + qg * 64 + l31) * 64 + hi * 8;
  half8 qf0[4], qf1[4];
  #pragma unroll
  for (int dc = 0; dc < 4; ++dc) {
    qf0[dc] = *reinterpret_cast<const half8*>(qbase + dc * 16);
    qf1[dc] = *reinterpret_cast<const half8*>(qbase + 2048 + dc * 16);  // +32 rows
  }

  const char* kfp = (const char*)KF + (size_t)bh * 524288 + (size_t)kvh * 262144 + lane * 16;
  const char* vfp = (const char*)VF + (size_t)bh * 524288 + (size_t)kvh * 262144 + lane * 16;

  f32x16 O00 = {}, O01 = {};   // q-set 0: d 0..31 / d 32..63
  f32x16 O10 = {}, O11 = {};   // q-set 1
  float m0 = -1e30f, l0 = 0.0f, m1 = -1e30f, l1 = 0.0f;

  auto loadF = [&]() {
    Frags f;
    f.v0 = *reinterpret_cast<const half8*>(vfp);
    f.v1 = *reinterpret_cast<const half8*>(vfp + 1024);
    f.v2 = *reinterpret_cast<const half8*>(vfp + 2048);
    f.v3 = *reinterpret_cast<const half8*>(vfp + 3072);
    f.k0 = *reinterpret_cast<const half8*>(kfp);
    f.k1 = *reinterpret_cast<const half8*>(kfp + 1024);
    f.k2 = *reinterpret_cast<const half8*>(kfp + 2048);
    f.k3 = *reinterpret_cast<const half8*>(kfp + 3072);
    vfp += 4096; kfp += 4096;
    return f;
  };

  auto compute = [&](const Frags& f) {
    // ---- S^T[kv][q] for both q-sets ----
    f32x16 S0 = {}, S1 = {};
    __builtin_amdgcn_s_setprio(1);
    S0 = __builtin_amdgcn_mfma_f32_32x32x16_f16(f.k0, qf0[0], S0, 0, 0, 0);
    S1 = __builtin_amdgcn_mfma_f32_32x32x16_f16(f.k0, qf1[0], S1, 0, 0, 0);
    S0 = __builtin_amdgcn_mfma_f32_32x32x16_f16(f.k1, qf0[1], S0, 0, 0, 0);
    S1 = __builtin_amdgcn_mfma_f32_32x32x16_f16(f.k1, qf1[1], S1, 0, 0, 0);
    S0 = __builtin_amdgcn_mfma_f32_32x32x16_f16(f.k2, qf0[2], S0, 0, 0, 0);
    S1 = __builtin_amdgcn_mfma_f32_32x32x16_f16(f.k2, qf1[2], S1, 0, 0, 0);
    S0 = __builtin_amdgcn_mfma_f32_32x32x16_f16(f.k3, qf0[3], S0, 0, 0, 0);
    S1 = __builtin_amdgcn_mfma_f32_32x32x16_f16(f.k3, qf1[3], S1, 0, 0, 0);
    __builtin_amdgcn_s_setprio(0);
    union U8 { unsigned u[4]; half8 h8; } p00, p01, p10, p11;
    // ---- softmax + pack, q-set 0 ----
    {
      float a0 = fmaxf(fmaxf(S0[0], S0[1]), fmaxf(S0[2], S0[3]));
      float a1 = fmaxf(fmaxf(S0[4], S0[5]), fmaxf(S0[6], S0[7]));
      float a2 = fmaxf(fmaxf(S0[8], S0[9]), fmaxf(S0[10], S0[11]));
      float a3 = fmaxf(fmaxf(S0[12], S0[13]), fmaxf(S0[14], S0[15]));
      float rmax = fmaxf(fmaxf(a0, a1), fmaxf(a2, a3));
      rmax = fmaxf(rmax, __shfl_xor(rmax, 32));
      if (!__all(rmax <= m0 + 8.0f)) {
        const float mnew = fmaxf(m0, rmax);
        const float fsc = __builtin_amdgcn_exp2f(m0 - mnew);
        l0 *= fsc;
        #pragma unroll
        for (int i = 0; i < 16; ++i) { O00[i] *= fsc; O01[i] *= fsc; }
        m0 = mnew;
      }
      #pragma unroll
      for (int i = 0; i < 16; ++i) S0[i] = __builtin_amdgcn_exp2f(S0[i] - m0);
      float s0 = (S0[0] + S0[1]) + (S0[2] + S0[3]);
      float s1 = (S0[4] + S0[5]) + (S0[6] + S0[7]);
      float s2 = (S0[8] + S0[9]) + (S0[10] + S0[11]);
      float s3 = (S0[12] + S0[13]) + (S0[14] + S0[15]);
      float rsum = (s0 + s1) + (s2 + s3);
      rsum += __shfl_xor(rsum, 32);
      l0 += rsum;
      p00.u[0] = pack_f16x2(S0[0], S0[1]);   p00.u[1] = pack_f16x2(S0[2], S0[3]);
      p00.u[2] = pack_f16x2(S0[4], S0[5]);   p00.u[3] = pack_f16x2(S0[6], S0[7]);
      p01.u[0] = pack_f16x2(S0[8], S0[9]);   p01.u[1] = pack_f16x2(S0[10], S0[11]);
      p01.u[2] = pack_f16x2(S0[12], S0[13]); p01.u[3] = pack_f16x2(S0[14], S0[15]);
    }
    // ---- softmax + pack, q-set 1 ----
    {
      float a0 = fmaxf(fmaxf(S1[0], S1[1]), fmaxf(S1[2], S1[3]));
      float a1 = fmaxf(fmaxf(S1[4], S1[5]), fmaxf(S1[6], S1[7]));
      float a2 = fmaxf(fmaxf(S1[8], S1[9]), fmaxf(S1[10], S1[11]));
      float a3 = fmaxf(fmaxf(S1[12], S1[13]), fmaxf(S1[14], S1[15]));
      float rmax = fmaxf(fmaxf(a0, a1), fmaxf(a2, a3));
      rmax = fmaxf(rmax, __shfl_xor(rmax, 32));
      if (!__all(rmax <= m1 + 8.0f)) {
        const float mnew = fmaxf(m1, rmax);
        const float fsc = __builtin_amdgcn_exp2f(m1 - mnew);
        l1 *= fsc;
        #pragma unroll
        for (int i = 0; i < 16; ++i) { O10[i] *= fsc; O11[i] *= fsc; }
        m1 = mnew;
      }
      #pragma unroll
      for (int i = 0; i < 16; ++i) S1[i] = __builtin_amdgcn_exp2f(S1[i] - m1);
      float s0 = (S1[0] + S1[1]) + (S1[2] + S1[3]);
      float s1 = (S1[4] + S1[5]) + (S1[6] + S1[7]);
      float s2 = (S1[8] + S1[9]) + (S1[10] + S1[11]);
      float s3 = (S1[12] + S1[13]) + (S1[14] + S1[15]);
      float rsum = (s0 + s1) + (s2 + s3);
      rsum += __shfl_xor(rsum, 32);
      l1 += rsum;
      p10.u[0] = pack_f16x2(S1[0], S1[1]);   p10.u[1] = pack_f16x2(S1[2], S1[3]);
      p10.u[2] = pack_f16x2(S1[4], S1[5]);   p10.u[3] = pack_f16x2(S1[6], S1[7]);
      p11.u[0] = pack_f16x2(S1[8], S1[9]);   p11.u[1] = pack_f16x2(S1[10], S1[11]);
      p11.u[2] = pack_f16x2(S1[12], S1[13]); p11.u[3] = pack_f16x2(S1[14], S1[15]);
    }
    // ---- O^T[d][q] += V^T . P^T (both q-sets share the V frags) ----
    __builtin_amdgcn_s_setprio(1);
    O00 = __builtin_amdgcn_mfma_f32_32x32x16_f16(f.v0, p00.h8, O00, 0, 0, 0);
    O10 = __builtin_amdgcn_mfma_f32_32x32x16_f16(f.v0, p10.h8, O10, 0, 0, 0);
    O00 = __builtin_amdgcn_mfma_f32_32x32x16_f16(f.v1, p01.h8, O00, 0, 0, 0);
    O10 = __builtin_amdgcn_mfma_f32_32x32x16_f16(f.v1, p11.h8, O10, 0, 0, 0);
    O01 = __builtin_amdgcn_mfma_f32_32x32x16_f16(f.v2, p00.h8, O01, 0, 0, 0);
    O11 = __builtin_amdgcn_mfma_f32_32x32x16_f16(f.v2, p10.h8, O11, 0, 0, 0);
    O01 = __builtin_amdgcn_mfma_f32_32x32x16_f16(f.v3, p01.h8, O01, 0, 0, 0);
    O11 = __builtin_amdgcn_mfma_f32_32x32x16_f16(f.v3, p11.h8, O11, 0, 0, 0);
    __builtin_amdgcn_s_setprio(0);
  };

  // ---- ping-pong: loads for tile t+1 issued before compute of tile t (no register copies) ----
  Frags fA = loadF();
  for (int tt = 0; tt < 31; ++tt) {
    Frags fB = loadF();
    compute(fA);
    fA = loadF();
    compute(fB);
  }
  {
    Frags fB = loadF();
    compute(fA);
    compute(fB);
  }

  // ---- split-KV merge, one q-set at a time (reuses the same LDS area) ----
  float* area = reinterpret_cast<float*>(smem) + qg * 2176;  // 2048 O + 64 m + 64 l floats
  #pragma unroll
  for (int qs = 0; qs < 2; ++qs) {
    const f32x16& Pd0 = qs ? O10 : O00;
    const f32x16& Pd1 = qs ? O11 : O01;
    const float mw = qs ? m1 : m0;
    const float lw = qs ? l1 : l0;
    __syncthreads();
    if (kvh) {
      #pragma unroll
      for (int r = 0; r < 16; ++r) {
        area[r * 64 + lane] = Pd0[r];
        area[(16 + r) * 64 + lane] = Pd1[r];
      }
      area[2048 + lane] = mw;
      area[2112 + lane] = lw;
    }
    __syncthreads();
    if (!kvh) {
      const float mB = area[2048 + lane], lB = area[2112 + lane];
      const float mx = fmaxf(mw, mB);
      const float fa = __builtin_amdgcn_exp2f(mw - mx);
      const float fb = __builtin_amdgcn_exp2f(mB - mx);
      const float inv = 1.0f / (lw * fa + lB * fb);
      const int qrow2 = qt * 128 + qg * 64 + qs * 32 + l31;
      bf16* ob = Out + ((size_t)b * 4096 + qrow2) * 512 + h * 64 + hi * 4;
      #pragma unroll
      for (int db = 0; db < 2; ++db) {
        #pragma unroll
        for (int rq = 0; rq < 4; ++rq) {
          const int r = rq * 4;
          float v0 = ((db ? Pd1[r + 0] : Pd0[r + 0]) * fa + area[(db * 16 + r + 0) * 64 + lane] * fb) * inv;
          float v1 = ((db ? Pd1[r + 1] : Pd0[r + 1]) * fa + area[(db * 16 + r + 1) * 64 + lane] * fb) * inv;
          float v2 = ((db ? Pd1[r + 2] : Pd0[r + 2]) * fa + area[(db * 16 + r + 2) * 64 + lane] * fb) * inv;
          float v3 = ((db ? Pd1[r + 3] : Pd0[r + 3]) * fa + area[(db * 16 + r + 3) * 64 + lane] * fb) * inv;
          uint2 st;
          st.x = pack_bf16x2(v0, v1);
          st.y = pack_bf16x2(v2, v3);
          *reinterpret_cast<uint2*>(ob + db * 32 + rq * 8) = st;
        }
      }
    }
  }
}

// ---------------- host ----------------
extern "C" void kernel_launch(void* const* d_in, const int* in_sizes, int n_in,
                              void* d_out, int out_size, void* d_ws, size_t ws_size,
                              hipStream_t stream) {
  const float* x      = (const float*)d_in[0];
  const float* ln1_g  = (const float*)d_in[1];
  const float* ln1_b  = (const float*)d_in[2];
  const float* ln2_g  = (const float*)d_in[3];
  const float* ln2_b  = (const float*)d_in[4];
  const float* qkv_w  = (const float*)d_in[5];
  const float* qkv_b  = (const float*)d_in[6];
  const float* proj_w = (const float*)d_in[7];
  const float* proj_b = (const float*)d_in[8];
  const float* fc1_w  = (const float*)d_in[9];
  const float* fc1_b  = (const float*)d_in[10];
  const float* fc2_w  = (const float*)d_in[11];
  const float* fc2_b  = (const float*)d_in[12];

  char* ws = (char*)d_ws;
  constexpr size_t o_qkvw = 0;
  constexpr size_t o_projw = 1572864;
  constexpr size_t o_fc1w  = 2097152;
  constexpr size_t o_fc2w  = 4194304;
  constexpr size_t o_h     = 6291456;
  constexpr size_t o_qkvC  = 14680064;
  constexpr size_t o_q     = 39845888;
  constexpr size_t o_k     = 48234496;
  constexpr size_t o_vt    = 56623104;
  constexpr size_t o_attn  = 65011712;
  constexpr size_t o_x2    = 73400320;
  constexpr size_t o_fc1o  = o_qkvC;
  constexpr size_t needed  = 90177536;
  if (ws_size < needed) return;

  bf16* qkvw_bf = (bf16*)(ws + o_qkvw);
  bf16* projw_bf = (bf16*)(ws + o_projw);
  bf16* fc1w_bf = (bf16*)(ws + o_fc1w);
  bf16* fc2w_bf = (bf16*)(ws + o_fc2w);
  bf16* h     = (bf16*)(ws + o_h);
  __half* qkvC = (__half*)(ws + o_qkvC);
  __half* q    = (__half*)(ws + o_q);
  __half* kf   = (__half*)(ws + o_k);
  __half* vf   = (__half*)(ws + o_vt);
  bf16* attn  = (bf16*)(ws + o_attn);
  float* x2   = (float*)(ws + o_x2);
  bf16* fc1o  = (bf16*)(ws + o_fc1o);
  float* out  = (float*)d_out;

  cvt_all<<<3072, 256, 0, stream>>>(qkv_w, qkvw_bf, proj_w, projw_bf, fc1_w, fc1w_bf, fc2_w, fc2w_bf);

  ln_kernel<<<2048, 256, 0, stream>>>(x, ln1_g, ln1_b, h);
  gemm_bt<3><<<dim3(64, 12), 256, 0, stream>>>(h, qkvw_bf, qkv_b, nullptr, qkvC, 8192, 1536, 512);
  reshape_qkv<<<dim3(64, 16), 256, 0, stream>>>(qkvC, q, kf, vf);
  attn_kernel<<<dim3(32, 16), 256, 0, stream>>>(q, kf, vf, attn);
  gemm_bt64<2><<<dim3(128, 8), 256, 0, stream>>>(attn, projw_bf, proj_b, x, x2, 8192, 512, 512);
  ln_kernel<<<2048, 256, 0, stream>>>(x2, ln2_g, ln2_b, h);
  gemm_bt<1><<<dim3(64, 16), 256, 0, stream>>>(h, fc1w_bf, fc1_b, nullptr, fc1o, 8192, 2048, 512);
  gemm_bt64<2><<<dim3(128, 8), 256, 0, stream>>>(fc1o, fc2w_bf, fc2_b, x2, out, 8192, 512, 2048);
}